// Round 2
// baseline (3846.357 us; speedup 1.0000x reference)
//
#include <hip/hip_runtime.h>
#include <hip/hip_bf16.h>

#define TBL 50
#define K 20
#define D 128
#define E 256
#define NB_B 2048
#define N1 (NB_B * K)   // 40960

// ws float offsets
#define OFF_WQT 0
#define OFF_WKT (OFF_WQT + 2*E*E)
#define OFF_WVT (OFF_WKT + 2*E*E)
#define OFF_WOT (OFF_WVT + 2*E*E)
#define OFF_W1T (OFF_WOT + 2*E*E)           // [2][384][128]
#define OFF_W2T (OFF_W1T + 2*384*D)         // [2][128][128]
#define OFF_NBR (OFF_W2T + 2*D*D)           // [N1][128] f32 layer-1 outputs

__global__ __launch_bounds__(256) void transpose_weights(
    const float* __restrict__ Wq, const float* __restrict__ Wk,
    const float* __restrict__ Wv, const float* __restrict__ Wo,
    const float* __restrict__ W1, const float* __restrict__ W2,
    float* __restrict__ ws)
{
  int idx = blockIdx.x * blockDim.x + threadIdx.x; // < 131072
  if (idx < 2*E*E) {
    int l = idx >> 16;
    int rem = idx & 65535;
    int i = rem >> 8, e = rem & 255;        // dst [l][i][e]
    int src = l*E*E + e*E + i;
    int dst = l*E*E + i*E + e;
    ws[OFF_WQT + dst] = Wq[src];
    ws[OFF_WKT + dst] = Wk[src];
    ws[OFF_WVT + dst] = Wv[src];
    ws[OFF_WOT + dst] = Wo[src];
  }
  if (idx < 2*384*D) {
    int l = idx / (384*D);
    int rem = idx % (384*D);
    int i = rem >> 7, d = rem & 127;        // dst [l][i][d], i<384
    ws[OFF_W1T + l*384*D + i*D + d] = W1[l*384*D + d*384 + i];
  }
  if (idx < 2*D*D) {
    int l = idx >> 14;
    int rem = idx & 16383;
    int i = rem >> 7, d = rem & 127;
    ws[OFF_W2T + l*D*D + i*D + d] = W2[l*D*D + d*D + i];
  }
}

// LAYER==0: inner attend (item node, l=0 weights), writes f32 rows to ws NBR
// LAYER==1: outer attend (user node, l=1 weights), writes f32 to d_out
template<int LAYER>
__global__ __launch_bounds__(256) void attend_kernel(
    const int* __restrict__ nodes, const int* __restrict__ edges, const int* __restrict__ tstamps,
    const int* __restrict__ u_neig, const int* __restrict__ u_edges,
    const int* __restrict__ u_times, const int* __restrict__ u_mask,
    const int* __restrict__ i_neig, const int* __restrict__ i_times, const int* __restrict__ i_mask,
    const float* __restrict__ user_emb, const float* __restrict__ item_emb,
    const float* __restrict__ time_w, const float* __restrict__ time_b,
    const float* __restrict__ bq, const float* __restrict__ bk, const float* __restrict__ bv,
    const float* __restrict__ bo, const float* __restrict__ b1, const float* __restrict__ b2,
    float* __restrict__ ws, float* __restrict__ out)
{
  __shared__ float smem[16000];     // 64000 B
  float* kvs = smem;                // [20][256]
  float* q   = smem + 5120;         // [256]
  float* qh  = smem + 5376;         // [256]
  float* khs = smem + 5632;         // [20][256]
  float* vhs = smem + 10752;        // [20][256]
  // reuse of kvs after projections:
  float* o_l  = kvs;                // [256]
  float* oo_l = kvs + 256;          // [256]
  float* h1_l = kvs + 512;          // [128]
  float* sc_l = kvs + 640;          // [40]
  float* av_l = kvs + 680;          // [40]
  __shared__ int nb_time[K];
  __shared__ int nb_mask[K];
  __shared__ int nb_src[K];
  __shared__ int s_meta[4];

  const int tid = threadIdx.x;

  if (tid == 0) {
    if (LAYER == 1) {
      int b = blockIdx.x;
      s_meta[0] = nodes[b];
      s_meta[1] = tstamps[b];
      s_meta[2] = edges[b];
      s_meta[3] = 1;
    } else {
      int j = blockIdx.x;
      int b = j / K, s = j % K;
      int pe = edges[b];
      int base = pe * TBL + (TBL - K) + s;
      s_meta[3] = u_mask[base];
      s_meta[0] = u_neig[base];
      s_meta[1] = u_times[base];
      s_meta[2] = u_edges[base];
    }
  }
  __syncthreads();

  if (LAYER == 0 && s_meta[3] == 0) {
    // invalid parent slot: gets softmax weight exactly 0 at layer 2
    // (exp(-1e9 - m) underflows); write zeros and exit
    if (tid < D) ws[OFF_NBR + (long)blockIdx.x * D + tid] = 0.f;
    return;
  }
  const int nodeId = s_meta[0];
  const int nodeTime = s_meta[1];
  const int edgeRow = s_meta[2];

  if (tid < K) {
    int base = edgeRow * TBL + (TBL - K) + tid;
    if (LAYER == 1) {
      nb_time[tid] = u_times[base];
      nb_mask[tid] = u_mask[base];
      nb_src[tid]  = blockIdx.x * K + tid;   // row in NBR
    } else {
      nb_time[tid] = i_times[base];
      nb_mask[tid] = i_mask[base];
      nb_src[tid]  = i_neig[base];           // user id
    }
  }
  // q = [node_feat, cos(time_b)]
  {
    const float* nf = (LAYER == 1 ? user_emb : item_emb) + (long)nodeId * D;
    if (tid < D) q[tid] = nf[tid];
    else         q[tid] = cosf(time_b[tid - D]);
  }
  __syncthreads();

  // kv rows: [feat(128) | cos(dt*w+b)(128)]
  for (int idx = tid; idx < K * E; idx += 256) {
    int r = idx >> 8, c = idx & 255;
    float v;
    if (c < D) {
      v = (LAYER == 1) ? ws[OFF_NBR + (long)nb_src[r] * D + c]
                       : user_emb[(long)nb_src[r] * D + c];
    } else {
      int dt = nodeTime - nb_time[r];
      v = cosf((float)dt * time_w[c - D] + time_b[c - D]);
    }
    kvs[idx] = v;
  }
  __syncthreads();

  bool anyv = false;
  #pragma unroll
  for (int k = 0; k < K; k++) anyv |= (nb_mask[k] > 0);

  // ---- projections: thread e owns output dim e ----
  {
    const int e = tid;
    const float* WQT = ws + OFF_WQT + LAYER*E*E;
    const float* WKT = ws + OFF_WKT + LAYER*E*E;
    const float* WVT = ws + OFF_WVT + LAYER*E*E;

    float aq = bq[LAYER*E + e];
    #pragma unroll 4
    for (int i = 0; i < E; i++) aq += q[i] * WQT[i*E + e];
    qh[e] = aq;

    float accK[K], accV[K];
    const float bke = bk[LAYER*E + e], bve = bv[LAYER*E + e];
    #pragma unroll
    for (int r = 0; r < K; r++) { accK[r] = bke; accV[r] = bve; }

    #pragma unroll 4
    for (int i = 0; i < E; i++) {
      float wk = WKT[i*E + e];
      float wv = WVT[i*E + e];
      #pragma unroll
      for (int r = 0; r < K; r++) {
        float f = kvs[r*E + i];
        accK[r] += f * wk;
        accV[r] += f * wv;
      }
    }
    __syncthreads();   // all threads done reading kvs (and q stays intact)
    #pragma unroll
    for (int r = 0; r < K; r++) {
      khs[r*E + e] = accK[r];
      vhs[r*E + e] = accV[r];
    }
  }
  __syncthreads();

  // ---- scores ----
  if (tid < 2*K) {
    int h = tid / K, k = tid % K;
    const float* qhh = qh + h*128;
    const float* khh = khs + k*E + h*128;
    float s = 0.f;
    for (int d = 0; d < 128; d++) s += qhh[d] * khh[d];
    s *= 0.08838834764831845f;  // 1/sqrt(128)
    sc_l[tid] = (nb_mask[k] > 0) ? s : -1e9f;
  }
  __syncthreads();
  if (tid < 2) {
    int h = tid;
    float m = -1e30f;
    for (int k = 0; k < K; k++) m = fmaxf(m, sc_l[h*K + k]);
    float tmp[K]; float ssum = 0.f;
    for (int k = 0; k < K; k++) { float ex = expf(sc_l[h*K + k] - m); tmp[k] = ex; ssum += ex; }
    float inv = 1.f / ssum;
    for (int k = 0; k < K; k++) av_l[h*K + k] = tmp[k] * inv;
  }
  __syncthreads();

  // ---- o = a @ v ----
  {
    const int e = tid;
    const int h = e >> 7;
    float oo = 0.f;
    #pragma unroll
    for (int k = 0; k < K; k++) oo += av_l[h*K + k] * vhs[k*E + e];
    o_l[e] = oo;
  }
  __syncthreads();
  // ---- Wo ----
  {
    const int e = tid;
    const float* WOT = ws + OFF_WOT + LAYER*E*E;
    float a = bo[LAYER*E + e];
    #pragma unroll 4
    for (int i = 0; i < E; i++) a += o_l[i] * WOT[i*E + e];
    oo_l[e] = anyv ? a : 0.f;
  }
  __syncthreads();
  // ---- FFN ----
  if (tid < D) {
    const float* W1T = ws + OFF_W1T + LAYER*384*D;
    float a = b1[LAYER*D + tid];
    #pragma unroll 4
    for (int i = 0; i < E; i++) a += oo_l[i] * W1T[i*D + tid];
    #pragma unroll 4
    for (int i = 0; i < D; i++) a += q[i] * W1T[(E + i)*D + tid];
    h1_l[tid] = fmaxf(a, 0.f);
  }
  __syncthreads();
  if (tid < D) {
    const float* W2T = ws + OFF_W2T + LAYER*D*D;
    float a = b2[LAYER*D + tid];
    #pragma unroll 4
    for (int i = 0; i < D; i++) a += h1_l[i] * W2T[i*D + tid];
    if (LAYER == 0) ws[OFF_NBR + (long)blockIdx.x * D + tid] = a;
    else            out[(long)blockIdx.x * D + tid] = a;   // f32 output
  }
}

extern "C" void kernel_launch(void* const* d_in, const int* in_sizes, int n_in,
                              void* d_out, int out_size, void* d_ws, size_t ws_size,
                              hipStream_t stream) {
  const int* nodes  = (const int*)d_in[0];
  const int* edges  = (const int*)d_in[1];
  const int* tst    = (const int*)d_in[2];
  const int* u_neig = (const int*)d_in[4];
  const int* u_edges= (const int*)d_in[5];
  const int* u_times= (const int*)d_in[6];
  const int* u_mask = (const int*)d_in[7];
  const int* i_neig = (const int*)d_in[8];
  const int* i_times= (const int*)d_in[10];
  const int* i_mask = (const int*)d_in[11];
  const float* user_emb = (const float*)d_in[12];
  const float* item_emb = (const float*)d_in[13];
  const float* time_w = (const float*)d_in[14];
  const float* time_b = (const float*)d_in[15];
  const float* Wq = (const float*)d_in[16]; const float* bq = (const float*)d_in[17];
  const float* Wk = (const float*)d_in[18]; const float* bk = (const float*)d_in[19];
  const float* Wv = (const float*)d_in[20]; const float* bv = (const float*)d_in[21];
  const float* Wo = (const float*)d_in[22]; const float* bo = (const float*)d_in[23];
  const float* W1 = (const float*)d_in[24]; const float* b1 = (const float*)d_in[25];
  const float* W2 = (const float*)d_in[26]; const float* b2 = (const float*)d_in[27];
  float* ws = (float*)d_ws;
  float* out = (float*)d_out;

  transpose_weights<<<dim3(512), dim3(256), 0, stream>>>(Wq, Wk, Wv, Wo, W1, W2, ws);

  attend_kernel<0><<<dim3(N1), dim3(256), 0, stream>>>(
      nodes, edges, tst, u_neig, u_edges, u_times, u_mask,
      i_neig, i_times, i_mask, user_emb, item_emb, time_w, time_b,
      bq, bk, bv, bo, b1, b2, ws, out);

  attend_kernel<1><<<dim3(NB_B), dim3(256), 0, stream>>>(
      nodes, edges, tst, u_neig, u_edges, u_times, u_mask,
      i_neig, i_times, i_mask, user_emb, item_emb, time_w, time_b,
      bq, bk, bv, bo, b1, b2, ws, out);
}

// Round 3
// 731.255 us; speedup vs baseline: 5.2599x; 5.2599x over previous
//
#include <hip/hip_runtime.h>
#include <hip/hip_bf16.h>

#define TBL 50
#define K 20
#define D 128
#define E 256
#define NB_B 2048
#define NSLOT (NB_B*K)     // 40960
#define G 8

// ws float offsets
#define OFF_WQT 0               // [2][128][256] feat-rows of Wq^T
#define OFF_QC  65536           // [2][256] qconst = bq + Wq[:,128:]·cos(time_b)
#define OFF_WVT 66048           // [2][256][256]
#define OFF_WOT 197120          // [2][256][256]
#define OFF_W1T 328192          // [2][384][128]
#define OFF_W2T 426496          // [2][128][128]
#define OFF_NBR 459264          // [40960][128] f32 layer-1 outputs
#define OFF_CNT 5702144         // int count; then int compact[40960]

// LDS float offsets (transposed [i][n] layouts, n fastest, G=8)
#define FEAT 0        // [128][8]
#define QH   1024     // [256][8]  (reused: o_t, then FFN1 partials)
#define GWS  3072     // [2][256][8] g then wsum (per-node column overwrite), then h1 [128][8]
#define OO   7168     // [256][8]  (reused: FFN2 partials)
#define AL   9216     // [2][20] scores->softmax weights
#define QB   9256     // [8][2]
#define ILDS 9280     // int region (<=128 ints)

__global__ __launch_bounds__(256) void precompute(
    const float* __restrict__ Wq, const float* __restrict__ Wv,
    const float* __restrict__ Wo, const float* __restrict__ W1,
    const float* __restrict__ W2, const float* __restrict__ bq,
    const float* __restrict__ time_b, float* __restrict__ ws)
{
  int idx = blockIdx.x * blockDim.x + threadIdx.x;   // < 131072
  if (idx < 65536) {   // WQT: [l][i<128][e]
    int l = idx >> 15, r = idx & 32767, i = r >> 8, e = r & 255;
    ws[OFF_WQT + idx] = Wq[l*65536 + e*256 + i];
  }
  if (idx < 131072) {  // WvT / WoT: [l][j][e]
    int l = idx >> 16, r = idx & 65535, j = r >> 8, e = r & 255;
    ws[OFF_WVT + idx] = Wv[l*65536 + e*256 + j];
    ws[OFF_WOT + idx] = Wo[l*65536 + e*256 + j];
  }
  if (idx < 98304) {   // W1T: [l][i<384][d]
    int l = idx / 49152, r = idx % 49152, i = r >> 7, d = r & 127;
    ws[OFF_W1T + idx] = W1[l*49152 + d*384 + i];
  }
  if (idx < 32768) {   // W2T: [l][i][d]
    int l = idx >> 14, r = idx & 16383, i = r >> 7, d = r & 127;
    ws[OFF_W2T + idx] = W2[l*16384 + d*128 + i];
  }
  if (idx < 512) {     // qconst
    int l = idx >> 8, e = idx & 255;
    float a = bq[l*256 + e];
    for (int j = 0; j < 128; j++)
      a += Wq[l*65536 + e*256 + 128 + j] * cosf(time_b[j]);
    ws[OFF_QC + idx] = a;
  }
}

__global__ __launch_bounds__(256) void zero_nbr(float* __restrict__ ws)
{
  int idx = blockIdx.x * blockDim.x + threadIdx.x;   // < 1310720
  ((float4*)(ws + OFF_NBR))[idx] = make_float4(0.f, 0.f, 0.f, 0.f);
  if (idx == 0) *(int*)(ws + OFF_CNT) = 0;
}

__global__ __launch_bounds__(256) void compact_valid(
    const int* __restrict__ edges, const int* __restrict__ u_mask,
    float* __restrict__ ws)
{
  int idx = blockIdx.x * blockDim.x + threadIdx.x;   // < 40960
  int b = idx / K, s = idx - b * K;
  int pe = edges[b];
  if (u_mask[pe*TBL + (TBL-K) + s] > 0) {
    int pos = atomicAdd((int*)(ws + OFF_CNT), 1);
    ((int*)(ws + OFF_CNT))[1 + pos] = idx;
  }
}

template<int LAYER>
__global__ __launch_bounds__(256, 4) void attend(
    const int* __restrict__ nodes, const int* __restrict__ edges, const int* __restrict__ tstamps,
    const int* __restrict__ u_edges, const int* __restrict__ u_neig,
    const int* __restrict__ u_times, const int* __restrict__ u_mask,
    const int* __restrict__ i_neig, const int* __restrict__ i_times, const int* __restrict__ i_mask,
    const float* __restrict__ user_emb, const float* __restrict__ item_emb,
    const float* __restrict__ time_w, const float* __restrict__ time_b,
    const float* __restrict__ Wk, const float* __restrict__ bk,
    const float* __restrict__ bv, const float* __restrict__ bo,
    const float* __restrict__ b1, const float* __restrict__ b2,
    float* __restrict__ ws, float* __restrict__ out)
{
  __shared__ float lds[9408];
  int* ilds = (int*)&lds[ILDS];
  // ilds: 0 nodeId[8], 8 nodeTime[8], 16 edgeRow[8], 24 slot[8],
  //       32 nbrow[20], 52 ntime[20], 72 nmask[20], 92 anyv[8], 100 act[8]
  const int tid = threadIdx.x;
  const int blk = blockIdx.x;
  const int l = LAYER;

  int count = (LAYER == 0) ? *(const int*)(ws + OFF_CNT) : NB_B;
  if (blk * G >= count) return;

  // P1: per-node meta
  if (tid < G) {
    int idx = blk * G + tid;
    int act = idx < count ? 1 : 0;
    int slot, nid, ntm, erow;
    if (LAYER == 0) {
      int ii = act ? idx : 0;
      slot = ((const int*)(ws + OFF_CNT))[1 + ii];
      int b = slot / K, s = slot - b * K;
      int base = edges[b]*TBL + (TBL-K) + s;
      nid = u_neig[base]; ntm = u_times[base]; erow = u_edges[base];
    } else {
      slot = idx; nid = nodes[idx]; ntm = tstamps[idx]; erow = edges[idx];
    }
    ilds[0+tid] = nid; ilds[8+tid] = ntm; ilds[16+tid] = erow;
    ilds[24+tid] = slot; ilds[100+tid] = act;
  }
  __syncthreads();

  // P2: node features -> feat_t[i][n]
  const float* nemb = (LAYER == 0) ? item_emb : user_emb;
  for (int it = 0; it < 4; ++it) {
    int idx = tid + it*256;
    int n = idx >> 7, i = idx & 127;
    lds[FEAT + i*8 + n] = nemb[(long)ilds[0+n]*D + i];
  }
  __syncthreads();

  // P3: qh = WQT·feat + qconst  -> qh_t[e][n]
  {
    const int e = tid;
    float acc[G];
    float qc = ws[OFF_QC + l*E + e];
    #pragma unroll
    for (int n = 0; n < G; n++) acc[n] = qc;
    const float* W = ws + OFF_WQT + l*128*E + e;
    for (int i = 0; i < 128; i++) {
      float w = W[i*E];
      float4 f0 = *(float4*)&lds[FEAT + i*8];
      float4 f1 = *(float4*)&lds[FEAT + i*8 + 4];
      acc[0] += f0.x*w; acc[1] += f0.y*w; acc[2] += f0.z*w; acc[3] += f0.w*w;
      acc[4] += f1.x*w; acc[5] += f1.y*w; acc[6] += f1.z*w; acc[7] += f1.w*w;
    }
    *(float4*)&lds[QH + e*8]     = make_float4(acc[0],acc[1],acc[2],acc[3]);
    *(float4*)&lds[QH + e*8 + 4] = make_float4(acc[4],acc[5],acc[6],acc[7]);
  }
  __syncthreads();

  // P4: g[h] = Wk_h^T qh_h  -> gws_t[h][j][n]  (Wk natural layout, coalesced)
  {
    const int j = tid;
    for (int h = 0; h < 2; h++) {
      float acc[G];
      #pragma unroll
      for (int n = 0; n < G; n++) acc[n] = 0.f;
      const float* W = Wk + l*E*E + (h*128)*E + j;
      for (int i = 0; i < 128; i++) {
        float w = W[i*E];
        float4 q0 = *(float4*)&lds[QH + (h*128+i)*8];
        float4 q1 = *(float4*)&lds[QH + (h*128+i)*8 + 4];
        acc[0] += q0.x*w; acc[1] += q0.y*w; acc[2] += q0.z*w; acc[3] += q0.w*w;
        acc[4] += q1.x*w; acc[5] += q1.y*w; acc[6] += q1.z*w; acc[7] += q1.w*w;
      }
      *(float4*)&lds[GWS + (h*256+j)*8]     = make_float4(acc[0],acc[1],acc[2],acc[3]);
      *(float4*)&lds[GWS + (h*256+j)*8 + 4] = make_float4(acc[4],acc[5],acc[6],acc[7]);
    }
  }
  __syncthreads();
  // qb[n][h] = qh_h · bk_h
  if (tid < 16) {
    int n = tid >> 1, h = tid & 1;
    float s = 0.f;
    for (int i = 0; i < 128; i++)
      s += lds[QH + (h*128+i)*8 + n] * bk[l*E + h*128 + i];
    lds[QB + n*2 + h] = s;
  }
  __syncthreads();

  const float* nbfeat = (LAYER == 0) ? user_emb : (ws + OFF_NBR);
  const float invsq = 0.08838834764831845f;  // 1/sqrt(128)

  // P5: per-node serial (scores -> softmax -> wsum overwrites g column n)
  #define GG(h, j) lds[GWS + ((h)*256 + (j))*8 + n]
  for (int n = 0; n < G; n++) {
    if (tid < K) {
      int base = ilds[16+n]*TBL + (TBL-K) + tid;
      if (LAYER == 0) {
        ilds[32+tid] = i_neig[base];
        ilds[52+tid] = i_times[base];
        ilds[72+tid] = i_mask[base];
      } else {
        ilds[32+tid] = (blk*G + n)*K + tid;
        ilds[52+tid] = u_times[base];
        ilds[72+tid] = u_mask[base];
      }
    }
    __syncthreads();
    // scores: lane (k,q) covers 16 feat dims + 16 time dims
    if (tid < 8*K) {
      int k = tid >> 3, q = tid & 7;
      const float* frow = nbfeat + (long)ilds[32+k]*D + q*16;
      float dt = (float)(ilds[8+n] - ilds[52+k]);
      float a0 = 0.f, a1 = 0.f;
      #pragma unroll
      for (int c4 = 0; c4 < 4; c4++) {
        float4 f = *(const float4*)&frow[c4*4];
        int j0 = q*16 + c4*4;
        a0 += f.x*GG(0,j0) + f.y*GG(0,j0+1) + f.z*GG(0,j0+2) + f.w*GG(0,j0+3);
        a1 += f.x*GG(1,j0) + f.y*GG(1,j0+1) + f.z*GG(1,j0+2) + f.w*GG(1,j0+3);
      }
      #pragma unroll
      for (int jj = 0; jj < 16; jj++) {
        int jt = q*16 + jj;
        float c = cosf(dt*time_w[jt] + time_b[jt]);
        a0 += c * GG(0, 128+jt);
        a1 += c * GG(1, 128+jt);
      }
      a0 += __shfl_down(a0, 4); a0 += __shfl_down(a0, 2); a0 += __shfl_down(a0, 1);
      a1 += __shfl_down(a1, 4); a1 += __shfl_down(a1, 2); a1 += __shfl_down(a1, 1);
      if (q == 0) {
        int m = ilds[72+k];
        float s0 = (a0 + lds[QB + n*2 + 0]) * invsq;
        float s1 = (a1 + lds[QB + n*2 + 1]) * invsq;
        lds[AL + k]     = m > 0 ? s0 : -1e9f;
        lds[AL + K + k] = m > 0 ? s1 : -1e9f;
      }
    }
    __syncthreads();
    if (tid < 2) {
      float mx = -1e30f;
      for (int k = 0; k < K; k++) mx = fmaxf(mx, lds[AL + tid*K + k]);
      float ex[K]; float s = 0.f;
      for (int k = 0; k < K; k++) { ex[k] = expf(lds[AL + tid*K + k] - mx); s += ex[k]; }
      float inv = 1.f / s;
      for (int k = 0; k < K; k++) lds[AL + tid*K + k] = ex[k] * inv;
    }
    if (tid == 2) {
      int any = 0;
      for (int k = 0; k < K; k++) any |= ilds[72+k];
      ilds[92+n] = any;
    }
    __syncthreads();
    // wsum -> overwrite g column n
    if (tid < 128) {
      int j = tid;
      float twj = time_w[j], tbj = time_b[j];
      float a0 = 0.f, a1 = 0.f;
      for (int k = 0; k < K; k++) {
        float dt = (float)(ilds[8+n] - ilds[52+k]);
        float c = cosf(dt*twj + tbj);
        a0 += lds[AL + k] * c;
        a1 += lds[AL + K + k] * c;
      }
      GG(0, 128+j) = a0; GG(1, 128+j) = a1;
    } else {
      int j = tid - 128;
      float a0 = 0.f, a1 = 0.f;
      for (int k = 0; k < K; k++) {
        float f = nbfeat[(long)ilds[32+k]*D + j];
        a0 += lds[AL + k] * f;
        a1 += lds[AL + K + k] * f;
      }
      GG(0, j) = a0; GG(1, j) = a1;
    }
    __syncthreads();
  }
  #undef GG

  // P6: o = WvT·wsum + bv  -> o_t in QH region
  {
    const int e = tid; const int h = e >> 7;
    float acc[G];
    float bvv = bv[l*E + e];
    #pragma unroll
    for (int n = 0; n < G; n++) acc[n] = bvv;
    const float* W = ws + OFF_WVT + l*E*E + e;
    for (int j = 0; j < E; j++) {
      float w = W[j*E];
      float4 s0 = *(float4*)&lds[GWS + (h*256+j)*8];
      float4 s1 = *(float4*)&lds[GWS + (h*256+j)*8 + 4];
      acc[0] += s0.x*w; acc[1] += s0.y*w; acc[2] += s0.z*w; acc[3] += s0.w*w;
      acc[4] += s1.x*w; acc[5] += s1.y*w; acc[6] += s1.z*w; acc[7] += s1.w*w;
    }
    __syncthreads();   // everyone done reading GWS & QH-free
    *(float4*)&lds[QH + e*8]     = make_float4(acc[0],acc[1],acc[2],acc[3]);
    *(float4*)&lds[QH + e*8 + 4] = make_float4(acc[4],acc[5],acc[6],acc[7]);
  }
  __syncthreads();

  // P7: oo = WoT·o + bo, zero if no valid neighbor -> OO region
  {
    const int e = tid;
    float acc[G];
    float bov = bo[l*E + e];
    #pragma unroll
    for (int n = 0; n < G; n++) acc[n] = bov;
    const float* W = ws + OFF_WOT + l*E*E + e;
    for (int i = 0; i < E; i++) {
      float w = W[i*E];
      float4 o0 = *(float4*)&lds[QH + i*8];
      float4 o1 = *(float4*)&lds[QH + i*8 + 4];
      acc[0] += o0.x*w; acc[1] += o0.y*w; acc[2] += o0.z*w; acc[3] += o0.w*w;
      acc[4] += o1.x*w; acc[5] += o1.y*w; acc[6] += o1.z*w; acc[7] += o1.w*w;
    }
    float v[G];
    #pragma unroll
    for (int n = 0; n < G; n++) v[n] = ilds[92+n] ? acc[n] : 0.f;
    __syncthreads();
    *(float4*)&lds[OO + e*8]     = make_float4(v[0],v[1],v[2],v[3]);
    *(float4*)&lds[OO + e*8 + 4] = make_float4(v[4],v[5],v[6],v[7]);
  }
  __syncthreads();

  // FFN1 partials (input = [oo(256), feat(128)]) -> QH region
  {
    const int dd = tid & 127, half = tid >> 7;
    float acc[G];
    #pragma unroll
    for (int n = 0; n < G; n++) acc[n] = 0.f;
    const float* W = ws + OFF_W1T + l*384*D + dd;
    if (half == 0) {
      for (int i = 0; i < 192; i++) {
        float w = W[i*D];
        float4 x0 = *(float4*)&lds[OO + i*8];
        float4 x1 = *(float4*)&lds[OO + i*8 + 4];
        acc[0] += x0.x*w; acc[1] += x0.y*w; acc[2] += x0.z*w; acc[3] += x0.w*w;
        acc[4] += x1.x*w; acc[5] += x1.y*w; acc[6] += x1.z*w; acc[7] += x1.w*w;
      }
    } else {
      for (int i = 192; i < 256; i++) {
        float w = W[i*D];
        float4 x0 = *(float4*)&lds[OO + i*8];
        float4 x1 = *(float4*)&lds[OO + i*8 + 4];
        acc[0] += x0.x*w; acc[1] += x0.y*w; acc[2] += x0.z*w; acc[3] += x0.w*w;
        acc[4] += x1.x*w; acc[5] += x1.y*w; acc[6] += x1.z*w; acc[7] += x1.w*w;
      }
      for (int i = 0; i < 128; i++) {
        float w = W[(256+i)*D];
        float4 x0 = *(float4*)&lds[FEAT + i*8];
        float4 x1 = *(float4*)&lds[FEAT + i*8 + 4];
        acc[0] += x0.x*w; acc[1] += x0.y*w; acc[2] += x0.z*w; acc[3] += x0.w*w;
        acc[4] += x1.x*w; acc[5] += x1.y*w; acc[6] += x1.z*w; acc[7] += x1.w*w;
      }
    }
    *(float4*)&lds[QH + (half*128+dd)*8]     = make_float4(acc[0],acc[1],acc[2],acc[3]);
    *(float4*)&lds[QH + (half*128+dd)*8 + 4] = make_float4(acc[4],acc[5],acc[6],acc[7]);
  }
  __syncthreads();
  // combine -> h1_t in GWS region
  for (int it = 0; it < 4; it++) {
    int idx = tid + it*256;
    int dd = idx >> 3, n = idx & 7;
    float v = lds[QH + dd*8 + n] + lds[QH + (128+dd)*8 + n] + b1[l*D + dd];
    lds[GWS + dd*8 + n] = fmaxf(v, 0.f);
  }
  __syncthreads();

  // FFN2 partials -> OO region
  {
    const int dd = tid & 127, half = tid >> 7;
    float acc[G];
    #pragma unroll
    for (int n = 0; n < G; n++) acc[n] = 0.f;
    const float* W = ws + OFF_W2T + l*D*D + dd;
    for (int i = half*64; i < half*64 + 64; i++) {
      float w = W[i*D];
      float4 h0 = *(float4*)&lds[GWS + i*8];
      float4 h1v = *(float4*)&lds[GWS + i*8 + 4];
      acc[0] += h0.x*w; acc[1] += h0.y*w; acc[2] += h0.z*w; acc[3] += h0.w*w;
      acc[4] += h1v.x*w; acc[5] += h1v.y*w; acc[6] += h1v.z*w; acc[7] += h1v.w*w;
    }
    __syncthreads();   // done reading OO (FFN1) before overwrite
    *(float4*)&lds[OO + (half*128+dd)*8]     = make_float4(acc[0],acc[1],acc[2],acc[3]);
    *(float4*)&lds[OO + (half*128+dd)*8 + 4] = make_float4(acc[4],acc[5],acc[6],acc[7]);
  }
  __syncthreads();
  // combine + write out
  for (int it = 0; it < 4; it++) {
    int idx = tid + it*256;
    int dd = idx & 127, n = idx >> 7;
    float v = lds[OO + dd*8 + n] + lds[OO + (128+dd)*8 + n] + b2[l*D + dd];
    if (LAYER == 0) {
      if (ilds[100+n]) ws[OFF_NBR + (long)ilds[24+n]*D + dd] = v;
    } else {
      out[(long)(blk*G + n)*D + dd] = v;
    }
  }
}

extern "C" void kernel_launch(void* const* d_in, const int* in_sizes, int n_in,
                              void* d_out, int out_size, void* d_ws, size_t ws_size,
                              hipStream_t stream) {
  const int* nodes  = (const int*)d_in[0];
  const int* edges  = (const int*)d_in[1];
  const int* tst    = (const int*)d_in[2];
  const int* u_neig = (const int*)d_in[4];
  const int* u_edges= (const int*)d_in[5];
  const int* u_times= (const int*)d_in[6];
  const int* u_mask = (const int*)d_in[7];
  const int* i_neig = (const int*)d_in[8];
  const int* i_times= (const int*)d_in[10];
  const int* i_mask = (const int*)d_in[11];
  const float* user_emb = (const float*)d_in[12];
  const float* item_emb = (const float*)d_in[13];
  const float* time_w = (const float*)d_in[14];
  const float* time_b = (const float*)d_in[15];
  const float* Wq = (const float*)d_in[16]; const float* bq = (const float*)d_in[17];
  const float* Wk = (const float*)d_in[18]; const float* bk = (const float*)d_in[19];
  const float* Wv = (const float*)d_in[20]; const float* bv = (const float*)d_in[21];
  const float* Wo = (const float*)d_in[22]; const float* bo = (const float*)d_in[23];
  const float* W1 = (const float*)d_in[24]; const float* b1 = (const float*)d_in[25];
  const float* W2 = (const float*)d_in[26]; const float* b2 = (const float*)d_in[27];
  float* ws = (float*)d_ws;
  float* out = (float*)d_out;

  precompute<<<dim3(512), dim3(256), 0, stream>>>(Wq, Wv, Wo, W1, W2, bq, time_b, ws);
  zero_nbr<<<dim3(5120), dim3(256), 0, stream>>>(ws);
  compact_valid<<<dim3(160), dim3(256), 0, stream>>>(edges, u_mask, ws);

  attend<0><<<dim3(NSLOT/G), dim3(256), 0, stream>>>(
      nodes, edges, tst, u_edges, u_neig, u_times, u_mask,
      i_neig, i_times, i_mask, user_emb, item_emb, time_w, time_b,
      Wk, bk, bv, bo, b1, b2, ws, out);

  attend<1><<<dim3(NB_B/G), dim3(256), 0, stream>>>(
      nodes, edges, tst, u_edges, u_neig, u_times, u_mask,
      i_neig, i_times, i_mask, user_emb, item_emb, time_w, time_b,
      Wk, bk, bv, bo, b1, b2, ws, out);
}

// Round 4
// 544.625 us; speedup vs baseline: 7.0624x; 1.3427x over previous
//
#include <hip/hip_runtime.h>
#include <hip/hip_bf16.h>

#define TBL 50
#define K 20
#define D 128
#define E 256
#define NB_B 2048
#define NSLOT (NB_B*K)     // 40960
#define G 8

// ws float offsets
#define OFF_A    0               // [l2][h2][i128][j256] = Wk_h^T · WqF_h
#define OFF_GC   131072          // [l2][h2][j256]
#define OFF_U    132096          // [l2][h2][i128]
#define OFF_CC   132608          // [l2][h2]
#define OFF_QC   132612          // [l2][e256]
#define OFF_WVT  133124          // [l2][j256][e256]
#define OFF_WOT  264196          // [l2][i256][e256]
#define OFF_W1T  395268          // [l2][i384][d128]
#define OFF_W2T  493572          // [l2][i128][d128]
#define OFF_NBR  526340          // [40960][128]
#define OFF_CNT  5769220         // int count; int compact[40960]

// LDS float offsets
#define FEAT 0        // [i128][n8]
#define QH   1024     // [e256][n8]; during P5 overlay: int nbm[480]
#define GWS  3072     // gT [n8][h2][j256]  ->  wsum [h2][e256][n8]  ->  h1 [d128][n8]
#define OO   7168     // [e256][n8]
#define AL   9216     // [n8][h2][k20]
#define QB   9536     // [n8][h2]
#define TW   9552     // [128]
#define TB   9680     // [128]
#define LDSF 9808

__device__ __forceinline__ float cosr(float x) {
  // cos(x) for |x| <= ~2e5, ~1e-5 abs accuracy (Cody-Waite + native cos)
  float kf = rintf(x * 0.15915494309189535f);
  float r = __fmaf_rn(kf, -6.28125f, x);
  r = __fmaf_rn(kf, -1.9353071795864769e-3f, r);
  return __cosf(r);
}

__global__ __launch_bounds__(256) void precompute1(
    const float* __restrict__ Wv, const float* __restrict__ Wo,
    const float* __restrict__ W1, const float* __restrict__ W2,
    const float* __restrict__ Wq, const float* __restrict__ bq,
    const float* __restrict__ time_b, float* __restrict__ ws)
{
  int idx = blockIdx.x*256 + threadIdx.x;   // < 131072
  if (idx < 131072) { int l = idx>>16, r = idx&65535, j = r>>8, e = r&255;
    ws[OFF_WVT+idx] = Wv[l*65536 + e*256 + j];
    ws[OFF_WOT+idx] = Wo[l*65536 + e*256 + j]; }
  if (idx < 98304) { int l = idx/49152, r = idx%49152, i = r>>7, d = r&127;
    ws[OFF_W1T+idx] = W1[l*49152 + d*384 + i]; }
  if (idx < 32768) { int l = idx>>14, r = idx&16383, i = r>>7, d = r&127;
    ws[OFF_W2T+idx] = W2[l*16384 + d*128 + i]; }
  if (idx < 512) { int l = idx>>8, e = idx&255;
    float a = bq[idx];
    for (int t = 0; t < 128; t++) a += Wq[l*65536 + e*256 + 128 + t]*cosf(time_b[t]);
    ws[OFF_QC+idx] = a; }
}

__global__ __launch_bounds__(256) void precompute2(
    const float* __restrict__ Wq, const float* __restrict__ Wk,
    const float* __restrict__ bk, float* __restrict__ ws)
{
  int b = blockIdx.x, t = threadIdx.x;
  if (b < 512) {           // A[l][h][i][j]: j = t
    int l = b >> 8, h = (b >> 7) & 1, i = b & 127;
    float s = 0.f;
    const float* wq = Wq + l*65536 + h*128*256 + i;
    const float* wk = Wk + l*65536 + h*128*256 + t;
    for (int m = 0; m < 128; m++) s += wq[m*256]*wk[m*256];
    ws[OFF_A + ((l*2+h)*128 + i)*256 + t] = s;
  } else {
    int q = b - 512, l = q >> 1, h = q & 1;
    { float s = 0.f;      // gc
      const float* qc = ws + OFF_QC + l*256 + h*128;
      const float* wk = Wk + l*65536 + h*128*256 + t;
      for (int m = 0; m < 128; m++) s += qc[m]*wk[m*256];
      ws[OFF_GC + (l*2+h)*256 + t] = s; }
    if (t < 128) {        // u
      float s = 0.f;
      const float* wq = Wq + l*65536 + h*128*256 + t;
      const float* bkp = bk + l*256 + h*128;
      for (int m = 0; m < 128; m++) s += wq[m*256]*bkp[m];
      ws[OFF_U + (l*2+h)*128 + t] = s; }
    if (t == 254) {       // cc
      float s = 0.f;
      const float* qc = ws + OFF_QC + l*256 + h*128;
      const float* bkp = bk + l*256 + h*128;
      for (int m = 0; m < 128; m++) s += qc[m]*bkp[m];
      ws[OFF_CC + l*2+h] = s; }
  }
}

__global__ __launch_bounds__(256) void zero_nbr(float* __restrict__ ws)
{
  int idx = blockIdx.x*256 + threadIdx.x;    // < 1310720
  ((float4*)(ws + OFF_NBR))[idx] = make_float4(0.f,0.f,0.f,0.f);
  if (idx == 0) *(int*)(ws + OFF_CNT) = 0;
}

__global__ __launch_bounds__(256) void compact_valid(
    const int* __restrict__ edges, const int* __restrict__ u_mask,
    float* __restrict__ ws)
{
  int idx = blockIdx.x*256 + threadIdx.x;    // < 40960
  int b = idx / K, s = idx - b*K;
  int pe = edges[b];
  if (u_mask[pe*TBL + (TBL-K) + s] > 0) {
    int pos = atomicAdd((int*)(ws + OFF_CNT), 1);
    ((int*)(ws + OFF_CNT))[1 + pos] = idx;
  }
}

template<int LAYER>
__global__ __launch_bounds__(256, 4) void attend(
    const int* __restrict__ nodes, const int* __restrict__ edges, const int* __restrict__ tstamps,
    const int* __restrict__ u_edges, const int* __restrict__ u_neig,
    const int* __restrict__ u_times, const int* __restrict__ u_mask,
    const int* __restrict__ i_neig, const int* __restrict__ i_times, const int* __restrict__ i_mask,
    const float* __restrict__ user_emb, const float* __restrict__ item_emb,
    const float* __restrict__ time_w, const float* __restrict__ time_b,
    const float* __restrict__ bv, const float* __restrict__ bo,
    const float* __restrict__ b1, const float* __restrict__ b2,
    float* __restrict__ ws, float* __restrict__ out)
{
  __shared__ float lds[LDSF];
  __shared__ int imem[48];   // 0 nid[8], 8 ntime[8], 16 erow[8], 24 slot[8], 32 anyv[8], 40 act[8]
  int* nbm = (int*)&lds[QH]; // [0:160) row, [160:320) time, [320:480) mask
  const int tid = threadIdx.x, blk = blockIdx.x, l = LAYER;

  int count = (LAYER == 0) ? *(const int*)(ws + OFF_CNT) : NB_B;
  if (blk*G >= count) return;

  if (tid < G) {
    int idx = blk*G + tid; int act = idx < count ? 1 : 0;
    int slot, nid, ntm, erow;
    if (LAYER == 0) {
      int ii = act ? idx : 0;
      slot = ((const int*)(ws + OFF_CNT))[1 + ii];
      int bb = slot / K, s = slot - bb*K;
      int base = edges[bb]*TBL + (TBL-K) + s;
      nid = u_neig[base]; ntm = u_times[base]; erow = u_edges[base];
    } else { slot = idx; nid = nodes[idx]; ntm = tstamps[idx]; erow = edges[idx]; }
    imem[tid] = nid; imem[8+tid] = ntm; imem[16+tid] = erow;
    imem[24+tid] = slot; imem[40+tid] = act;
  }
  if (tid < 128) { lds[TW+tid] = time_w[tid]; lds[TB+tid] = time_b[tid]; }
  __syncthreads();

  // FEAT + neighbor meta
  const float* nemb = (LAYER == 0) ? item_emb : user_emb;
  #pragma unroll
  for (int it = 0; it < 4; it++) {
    int idx = tid + it*256, i = idx >> 3, n = idx & 7;
    lds[FEAT + i*8 + n] = nemb[(long)imem[n]*D + i];
  }
  if (tid < G*K) {
    int n = tid / K, k = tid - n*K;
    int base = imem[16+n]*TBL + (TBL-K) + k;
    if (LAYER == 0) { nbm[tid] = i_neig[base]; nbm[160+tid] = i_times[base]; nbm[320+tid] = i_mask[base]; }
    else            { nbm[tid] = (blk*G+n)*K + k; nbm[160+tid] = u_times[base]; nbm[320+tid] = u_mask[base]; }
  }
  __syncthreads();

  // g: gT[n][h][j] = A_h·feat + gc ; qb via u,cc
  #pragma unroll
  for (int h = 0; h < 2; h++) {
    const int j = tid;
    float acc0,acc1,acc2,acc3,acc4,acc5,acc6,acc7;
    { float g0 = ws[OFF_GC + (l*2+h)*256 + j];
      acc0=acc1=acc2=acc3=acc4=acc5=acc6=acc7=g0; }
    const float* W = ws + OFF_A + ((l*2+h)*128)*256 + j;
    #pragma unroll 4
    for (int i = 0; i < 128; i++) {
      float w = W[i*256];
      float4 f0 = *(const float4*)&lds[FEAT + i*8];
      float4 f1 = *(const float4*)&lds[FEAT + i*8 + 4];
      acc0 += f0.x*w; acc1 += f0.y*w; acc2 += f0.z*w; acc3 += f0.w*w;
      acc4 += f1.x*w; acc5 += f1.y*w; acc6 += f1.z*w; acc7 += f1.w*w;
    }
    lds[GWS + 0*512 + h*256 + j] = acc0; lds[GWS + 1*512 + h*256 + j] = acc1;
    lds[GWS + 2*512 + h*256 + j] = acc2; lds[GWS + 3*512 + h*256 + j] = acc3;
    lds[GWS + 4*512 + h*256 + j] = acc4; lds[GWS + 5*512 + h*256 + j] = acc5;
    lds[GWS + 6*512 + h*256 + j] = acc6; lds[GWS + 7*512 + h*256 + j] = acc7;
  }
  if (tid < 16) {
    int n = tid >> 1, h = tid & 1;
    float s = ws[OFF_CC + l*2 + h];
    const float* u = ws + OFF_U + (l*2+h)*128;
    for (int i = 0; i < 128; i++) s += lds[FEAT + i*8 + n]*u[i];
    lds[QB + tid] = s;
  }
  __syncthreads();

  const float* nbfeat = (LAYER == 0) ? user_emb : (ws + OFF_NBR);

  // Phase A: all 160 (n,k) scores in parallel
  if (tid < G*K) {
    int n = tid / K, k = tid - n*K;
    float dtf = (float)(imem[8+n] - nbm[160+tid]);
    const float4* fr = (const float4*)(nbfeat + (long)nbm[tid]*D);
    const float4* g4 = (const float4*)&lds[GWS + n*512];
    float a0 = 0.f, a1 = 0.f;
    #pragma unroll 4
    for (int c = 0; c < 32; c++) {
      float4 f = fr[c];
      float4 g0 = g4[c];       // head0 feat dims
      float4 g1 = g4[64 + c];  // head1 feat dims
      a0 += f.x*g0.x + f.y*g0.y + f.z*g0.z + f.w*g0.w;
      a1 += f.x*g1.x + f.y*g1.y + f.z*g1.z + f.w*g1.w;
    }
    const float4* tw4 = (const float4*)&lds[TW];
    const float4* tb4 = (const float4*)&lds[TB];
    #pragma unroll 2
    for (int c = 0; c < 32; c++) {
      float4 tw = tw4[c], tb = tb4[c];
      float4 cv;
      cv.x = cosr(__fadd_rn(__fmul_rn(dtf, tw.x), tb.x));
      cv.y = cosr(__fadd_rn(__fmul_rn(dtf, tw.y), tb.y));
      cv.z = cosr(__fadd_rn(__fmul_rn(dtf, tw.z), tb.z));
      cv.w = cosr(__fadd_rn(__fmul_rn(dtf, tw.w), tb.w));
      float4 g0 = g4[32 + c];  // head0 time dims
      float4 g1 = g4[96 + c];  // head1 time dims
      a0 += cv.x*g0.x + cv.y*g0.y + cv.z*g0.z + cv.w*g0.w;
      a1 += cv.x*g1.x + cv.y*g1.y + cv.z*g1.z + cv.w*g1.w;
    }
    float qb0 = lds[QB + (n<<1)], qb1 = lds[QB + (n<<1) + 1];
    int m = nbm[320+tid];
    const float invsq = 0.08838834764831845f;
    lds[AL + n*40 + k]      = m > 0 ? (a0 + qb0)*invsq : -1e9f;
    lds[AL + n*40 + 20 + k] = m > 0 ? (a1 + qb1)*invsq : -1e9f;
  }
  __syncthreads();

  // Phase B: softmax (16 threads)
  if (tid < 16) {
    int n = tid >> 1, h = tid & 1;
    float* a = &lds[AL + n*40 + h*20];
    float mx = -1e30f;
    for (int k = 0; k < K; k++) mx = fmaxf(mx, a[k]);
    float s = 0.f;
    for (int k = 0; k < K; k++) { float e = __expf(a[k]-mx); a[k] = e; s += e; }
    float inv = 1.f/s;
    for (int k = 0; k < K; k++) a[k] *= inv;
    if (h == 0) { int any = 0;
      for (int k = 0; k < K; k++) any |= nbm[320 + n*20 + k];
      imem[32+n] = any; }
  }
  __syncthreads();

  // Phase C: wsum[h][e][n] (overwrites gT region)
  {
    int n = tid >> 5, e0 = tid & 31;
    const float* a0p = &lds[AL + n*40];
    const float* a1p = &lds[AL + n*40 + 20];
    #pragma unroll
    for (int it = 0; it < 8; it++) {
      int e = e0 + it*32;
      float w0 = 0.f, w1 = 0.f;
      if (it < 4) {
        for (int k = 0; k < K; k++) {
          float f = nbfeat[(long)nbm[n*20+k]*D + e];
          w0 += a0p[k]*f; w1 += a1p[k]*f;
        }
      } else {
        int j = e - 128;
        float twj = lds[TW+j], tbj = lds[TB+j];
        for (int k = 0; k < K; k++) {
          float dtf = (float)(imem[8+n] - nbm[160 + n*20 + k]);
          float c = cosr(__fadd_rn(__fmul_rn(dtf, twj), tbj));
          w0 += a0p[k]*c; w1 += a1p[k]*c;
        }
      }
      lds[GWS + e*8 + n]         = w0;
      lds[GWS + (256+e)*8 + n]   = w1;
    }
  }
  __syncthreads();

  // P6: o = WvT·wsum + bv -> QH
  {
    const int e = tid, h = e >> 7;
    float acc0,acc1,acc2,acc3,acc4,acc5,acc6,acc7;
    { float bb = bv[l*E+e]; acc0=acc1=acc2=acc3=acc4=acc5=acc6=acc7=bb; }
    const float* W = ws + OFF_WVT + l*65536 + e;
    #pragma unroll 4
    for (int j = 0; j < 256; j++) {
      float w = W[j*256];
      float4 s0 = *(const float4*)&lds[GWS + (h*256+j)*8];
      float4 s1 = *(const float4*)&lds[GWS + (h*256+j)*8 + 4];
      acc0 += s0.x*w; acc1 += s0.y*w; acc2 += s0.z*w; acc3 += s0.w*w;
      acc4 += s1.x*w; acc5 += s1.y*w; acc6 += s1.z*w; acc7 += s1.w*w;
    }
    *(float4*)&lds[QH + e*8]     = make_float4(acc0,acc1,acc2,acc3);
    *(float4*)&lds[QH + e*8 + 4] = make_float4(acc4,acc5,acc6,acc7);
  }
  __syncthreads();

  // P7: oo = WoT·o + bo, anyv mask -> OO
  {
    const int e = tid;
    float acc0,acc1,acc2,acc3,acc4,acc5,acc6,acc7;
    { float bb = bo[l*E+e]; acc0=acc1=acc2=acc3=acc4=acc5=acc6=acc7=bb; }
    const float* W = ws + OFF_WOT + l*65536 + e;
    #pragma unroll 4
    for (int i = 0; i < 256; i++) {
      float w = W[i*256];
      float4 o0 = *(const float4*)&lds[QH + i*8];
      float4 o1 = *(const float4*)&lds[QH + i*8 + 4];
      acc0 += o0.x*w; acc1 += o0.y*w; acc2 += o0.z*w; acc3 += o0.w*w;
      acc4 += o1.x*w; acc5 += o1.y*w; acc6 += o1.z*w; acc7 += o1.w*w;
    }
    float v0 = imem[32+0]?acc0:0.f, v1 = imem[32+1]?acc1:0.f;
    float v2 = imem[32+2]?acc2:0.f, v3 = imem[32+3]?acc3:0.f;
    float v4 = imem[32+4]?acc4:0.f, v5 = imem[32+5]?acc5:0.f;
    float v6 = imem[32+6]?acc6:0.f, v7 = imem[32+7]?acc7:0.f;
    *(float4*)&lds[OO + e*8]     = make_float4(v0,v1,v2,v3);
    *(float4*)&lds[OO + e*8 + 4] = make_float4(v4,v5,v6,v7);
  }
  __syncthreads();

  // FFN1 partials -> QH
  {
    const int dd = tid & 127, half = tid >> 7;
    float acc0,acc1,acc2,acc3,acc4,acc5,acc6,acc7;
    acc0=acc1=acc2=acc3=acc4=acc5=acc6=acc7=0.f;
    const float* W = ws + OFF_W1T + l*384*D + dd;
    if (half == 0) {
      #pragma unroll 4
      for (int i = 0; i < 192; i++) {
        float w = W[i*D];
        float4 x0 = *(const float4*)&lds[OO + i*8];
        float4 x1 = *(const float4*)&lds[OO + i*8 + 4];
        acc0 += x0.x*w; acc1 += x0.y*w; acc2 += x0.z*w; acc3 += x0.w*w;
        acc4 += x1.x*w; acc5 += x1.y*w; acc6 += x1.z*w; acc7 += x1.w*w;
      }
    } else {
      #pragma unroll 4
      for (int i = 192; i < 256; i++) {
        float w = W[i*D];
        float4 x0 = *(const float4*)&lds[OO + i*8];
        float4 x1 = *(const float4*)&lds[OO + i*8 + 4];
        acc0 += x0.x*w; acc1 += x0.y*w; acc2 += x0.z*w; acc3 += x0.w*w;
        acc4 += x1.x*w; acc5 += x1.y*w; acc6 += x1.z*w; acc7 += x1.w*w;
      }
      #pragma unroll 4
      for (int i = 0; i < 128; i++) {
        float w = W[(256+i)*D];
        float4 x0 = *(const float4*)&lds[FEAT + i*8];
        float4 x1 = *(const float4*)&lds[FEAT + i*8 + 4];
        acc0 += x0.x*w; acc1 += x0.y*w; acc2 += x0.z*w; acc3 += x0.w*w;
        acc4 += x1.x*w; acc5 += x1.y*w; acc6 += x1.z*w; acc7 += x1.w*w;
      }
    }
    *(float4*)&lds[QH + (half*128+dd)*8]     = make_float4(acc0,acc1,acc2,acc3);
    *(float4*)&lds[QH + (half*128+dd)*8 + 4] = make_float4(acc4,acc5,acc6,acc7);
  }
  __syncthreads();
  // h1 combine -> GWS
  #pragma unroll
  for (int it = 0; it < 4; it++) {
    int idx = tid + it*256, dd = idx >> 3, n = idx & 7;
    float v = lds[QH + dd*8 + n] + lds[QH + (128+dd)*8 + n] + b1[l*D + dd];
    lds[GWS + dd*8 + n] = fmaxf(v, 0.f);
  }
  __syncthreads();

  // FFN2 partials -> OO
  {
    const int dd = tid & 127, half = tid >> 7;
    float acc0,acc1,acc2,acc3,acc4,acc5,acc6,acc7;
    acc0=acc1=acc2=acc3=acc4=acc5=acc6=acc7=0.f;
    const float* W = ws + OFF_W2T + l*D*D + dd;
    #pragma unroll 4
    for (int i = half*64; i < half*64 + 64; i++) {
      float w = W[i*D];
      float4 h0 = *(const float4*)&lds[GWS + i*8];
      float4 h1 = *(const float4*)&lds[GWS + i*8 + 4];
      acc0 += h0.x*w; acc1 += h0.y*w; acc2 += h0.z*w; acc3 += h0.w*w;
      acc4 += h1.x*w; acc5 += h1.y*w; acc6 += h1.z*w; acc7 += h1.w*w;
    }
    __syncthreads();
    *(float4*)&lds[OO + (half*128+dd)*8]     = make_float4(acc0,acc1,acc2,acc3);
    *(float4*)&lds[OO + (half*128+dd)*8 + 4] = make_float4(acc4,acc5,acc6,acc7);
  }
  __syncthreads();
  // out combine
  #pragma unroll
  for (int it = 0; it < 4; it++) {
    int idx = tid + it*256, dd = idx & 127, n = idx >> 7;
    float v = lds[OO + dd*8 + n] + lds[OO + (128+dd)*8 + n] + b2[l*D + dd];
    if (LAYER == 0) { if (imem[40+n]) ws[OFF_NBR + (long)imem[24+n]*D + dd] = v; }
    else            out[(long)(blk*G + n)*D + dd] = v;
  }
}

extern "C" void kernel_launch(void* const* d_in, const int* in_sizes, int n_in,
                              void* d_out, int out_size, void* d_ws, size_t ws_size,
                              hipStream_t stream) {
  const int* nodes  = (const int*)d_in[0];
  const int* edges  = (const int*)d_in[1];
  const int* tst    = (const int*)d_in[2];
  const int* u_neig = (const int*)d_in[4];
  const int* u_edges= (const int*)d_in[5];
  const int* u_times= (const int*)d_in[6];
  const int* u_mask = (const int*)d_in[7];
  const int* i_neig = (const int*)d_in[8];
  const int* i_times= (const int*)d_in[10];
  const int* i_mask = (const int*)d_in[11];
  const float* user_emb = (const float*)d_in[12];
  const float* item_emb = (const float*)d_in[13];
  const float* time_w = (const float*)d_in[14];
  const float* time_b = (const float*)d_in[15];
  const float* Wq = (const float*)d_in[16]; const float* bq = (const float*)d_in[17];
  const float* Wk = (const float*)d_in[18]; const float* bk = (const float*)d_in[19];
  const float* bv = (const float*)d_in[21];
  const float* bo = (const float*)d_in[23];
  const float* W1 = (const float*)d_in[24]; const float* b1 = (const float*)d_in[25];
  const float* W2 = (const float*)d_in[26]; const float* b2 = (const float*)d_in[27];
  const float* Wv = (const float*)d_in[20];
  const float* Wo = (const float*)d_in[22];
  float* ws = (float*)d_ws;
  float* out = (float*)d_out;

  precompute1<<<dim3(512), dim3(256), 0, stream>>>(Wv, Wo, W1, W2, Wq, bq, time_b, ws);
  precompute2<<<dim3(516), dim3(256), 0, stream>>>(Wq, Wk, bk, ws);
  zero_nbr<<<dim3(5120), dim3(256), 0, stream>>>(ws);
  compact_valid<<<dim3(160), dim3(256), 0, stream>>>(edges, u_mask, ws);

  attend<0><<<dim3(NSLOT/G), dim3(256), 0, stream>>>(
      nodes, edges, tst, u_edges, u_neig, u_times, u_mask,
      i_neig, i_times, i_mask, user_emb, item_emb, time_w, time_b,
      bv, bo, b1, b2, ws, out);

  attend<1><<<dim3(NB_B/G), dim3(256), 0, stream>>>(
      nodes, edges, tst, u_edges, u_neig, u_times, u_mask,
      i_neig, i_times, i_mask, user_emb, item_emb, time_w, time_b,
      bv, bo, b1, b2, ws, out);
}

// Round 5
// 391.424 us; speedup vs baseline: 9.8266x; 1.3914x over previous
//
#include <hip/hip_runtime.h>
#include <hip/hip_bf16.h>

#define TBL 50
#define K 20
#define D 128
#define E 256
#define NB_B 2048
#define NSLOT (NB_B*K)     // 40960
#define G 16

// ws float offsets
#define OFF_A    0               // [l2][h2][i128][j256] = Wk_h^T · WqF_h
#define OFF_GC   131072          // [l2][h2][j256]
#define OFF_U    132096          // [l2][h2][i128]
#define OFF_CC   132608          // [l2][h2]
#define OFF_QC   132612          // [l2][e256]
#define OFF_WVT  133124          // [l2][j256][e256]
#define OFF_WOT  264196          // [l2][i256][e256]
#define OFF_W1T  395268          // [l2][i384][d128]
#define OFF_W2T  493572          // [l2][i128][d128]
#define OFF_NBR  526340          // [40960][128]
#define OFF_CNT  5769220         // int count; int compact[40960]

// LDS float offsets
#define FEAT 0        // [i128][n16]
#define QH   2048     // [e256][n16]; overlay early: int nbm[960]
#define GWS  6144     // g: [n16][h2][j256] -> wsum [h2][e256][n16] -> oo [e256][n16](low half)
#define H1R  10240    // h1 [d128][n16] (upper half of GWS)
#define AL   14336    // [n16][h2][k20]
#define QB   14976    // [n16][h2]
#define TW   15008    // [128]
#define TB   15136    // [128]
#define LDSF 15264

__device__ __forceinline__ float cosr(float x) {
  float kf = rintf(x * 0.15915494309189535f);
  float r = __fmaf_rn(kf, -6.28125f, x);
  r = __fmaf_rn(kf, -1.9353071795864769e-3f, r);
  return __cosf(r);
}

__global__ __launch_bounds__(256) void precompute1(
    const float* __restrict__ Wv, const float* __restrict__ Wo,
    const float* __restrict__ W1, const float* __restrict__ W2,
    const float* __restrict__ Wq, const float* __restrict__ bq,
    const float* __restrict__ time_b, float* __restrict__ ws)
{
  int idx = blockIdx.x*256 + threadIdx.x;   // < 131072
  if (idx < 131072) { int l = idx>>16, r = idx&65535, j = r>>8, e = r&255;
    ws[OFF_WVT+idx] = Wv[l*65536 + e*256 + j];
    ws[OFF_WOT+idx] = Wo[l*65536 + e*256 + j]; }
  if (idx < 98304) { int l = idx/49152, r = idx%49152, i = r>>7, d = r&127;
    ws[OFF_W1T+idx] = W1[l*49152 + d*384 + i]; }
  if (idx < 32768) { int l = idx>>14, r = idx&16383, i = r>>7, d = r&127;
    ws[OFF_W2T+idx] = W2[l*16384 + d*128 + i]; }
  if (idx < 512) { int l = idx>>8, e = idx&255;
    float a = bq[idx];
    for (int t = 0; t < 128; t++) a += Wq[l*65536 + e*256 + 128 + t]*cosf(time_b[t]);
    ws[OFF_QC+idx] = a; }
}

__global__ __launch_bounds__(256) void precompute2(
    const float* __restrict__ Wq, const float* __restrict__ Wk,
    const float* __restrict__ bk, float* __restrict__ ws)
{
  int b = blockIdx.x, t = threadIdx.x;
  if (b < 512) {           // A[l][h][i][j]: j = t
    int l = b >> 8, h = (b >> 7) & 1, i = b & 127;
    float s = 0.f;
    const float* wq = Wq + l*65536 + h*128*256 + i;
    const float* wk = Wk + l*65536 + h*128*256 + t;
    for (int m = 0; m < 128; m++) s += wq[m*256]*wk[m*256];
    ws[OFF_A + ((l*2+h)*128 + i)*256 + t] = s;
  } else {
    int q = b - 512, l = q >> 1, h = q & 1;
    { float s = 0.f;      // gc
      const float* qc = ws + OFF_QC + l*256 + h*128;
      const float* wk = Wk + l*65536 + h*128*256 + t;
      for (int m = 0; m < 128; m++) s += qc[m]*wk[m*256];
      ws[OFF_GC + (l*2+h)*256 + t] = s; }
    if (t < 128) {        // u
      float s = 0.f;
      const float* wq = Wq + l*65536 + h*128*256 + t;
      const float* bkp = bk + l*256 + h*128;
      for (int m = 0; m < 128; m++) s += wq[m*256]*bkp[m];
      ws[OFF_U + (l*2+h)*128 + t] = s; }
    if (t == 254) {       // cc
      float s = 0.f;
      const float* qc = ws + OFF_QC + l*256 + h*128;
      const float* bkp = bk + l*256 + h*128;
      for (int m = 0; m < 128; m++) s += qc[m]*bkp[m];
      ws[OFF_CC + l*2+h] = s; }
  }
}

__global__ void zero_cnt(float* __restrict__ ws)
{
  if (threadIdx.x == 0) *(int*)(ws + OFF_CNT) = 0;
}

__global__ __launch_bounds__(256) void compact_valid(
    const int* __restrict__ edges, const int* __restrict__ u_mask,
    float* __restrict__ ws)
{
  int idx = blockIdx.x*256 + threadIdx.x;    // < 40960
  int b = idx / K, s = idx - b*K;
  int pe = edges[b];
  if (u_mask[pe*TBL + (TBL-K) + s] > 0) {
    int pos = atomicAdd((int*)(ws + OFF_CNT), 1);
    ((int*)(ws + OFF_CNT))[1 + pos] = idx;
  }
}

template<int LAYER>
__global__ __launch_bounds__(256, 2) void attend(
    const int* __restrict__ nodes, const int* __restrict__ edges, const int* __restrict__ tstamps,
    const int* __restrict__ u_edges, const int* __restrict__ u_neig,
    const int* __restrict__ u_times, const int* __restrict__ u_mask,
    const int* __restrict__ i_neig, const int* __restrict__ i_times, const int* __restrict__ i_mask,
    const float* __restrict__ user_emb, const float* __restrict__ item_emb,
    const float* __restrict__ time_w, const float* __restrict__ time_b,
    const float* __restrict__ bv, const float* __restrict__ bo,
    const float* __restrict__ b1, const float* __restrict__ b2,
    float* __restrict__ ws, float* __restrict__ out)
{
  __shared__ float lds[LDSF];
  __shared__ int imem[96];   // 0 nid, 16 ntime, 32 erow, 48 slot, 64 anyv, 80 act
  int* nbm = (int*)&lds[QH]; // [0:320) row, [320:640) time, [640:960) mask
  const int tid = threadIdx.x, blk = blockIdx.x, l = LAYER;

  int count = (LAYER == 0) ? *(const int*)(ws + OFF_CNT) : NB_B;
  if (blk*G >= count) return;

  if (tid < G) {
    int idx = blk*G + tid; int act = idx < count ? 1 : 0;
    int slot, nid, ntm, erow;
    if (LAYER == 0) {
      int ii = act ? idx : 0;
      slot = ((const int*)(ws + OFF_CNT))[1 + ii];
      int bb = slot / K, s = slot - bb*K;
      int base = edges[bb]*TBL + (TBL-K) + s;
      nid = u_neig[base]; ntm = u_times[base]; erow = u_edges[base];
    } else { slot = idx; nid = nodes[idx]; ntm = tstamps[idx]; erow = edges[idx]; }
    imem[tid] = nid; imem[16+tid] = ntm; imem[32+tid] = erow;
    imem[48+tid] = slot; imem[80+tid] = act;
  }
  if (tid < 128) { lds[TW+tid] = time_w[tid]; lds[TB+tid] = time_b[tid]; }
  __syncthreads();

  // FEAT[i][n] + neighbor meta
  const float* nemb = (LAYER == 0) ? item_emb : user_emb;
  #pragma unroll
  for (int it = 0; it < 8; it++) {
    int idx = tid + it*256, n = idx >> 7, i = idx & 127;
    lds[FEAT + i*16 + n] = nemb[(long)imem[n]*D + i];
  }
  #pragma unroll
  for (int it = 0; it < 2; it++) {
    int p = tid + it*256;
    if (p < G*K) {
      int n = p / K, k = p - n*K;
      int base = imem[32+n]*TBL + (TBL-K) + k;
      if (LAYER == 0) { nbm[p] = i_neig[base]; nbm[320+p] = i_times[base]; nbm[640+p] = i_mask[base]; }
      else            { nbm[p] = (blk*G+n)*K + k; nbm[320+p] = u_times[base]; nbm[640+p] = u_mask[base]; }
    }
  }
  __syncthreads();

  // g phase: both heads together; gT[n][h][j]
  {
    const int j = tid;
    float a0[G], a1[G];
    { float g00 = ws[OFF_GC + (l*2+0)*256 + j];
      float g01 = ws[OFF_GC + (l*2+1)*256 + j];
      #pragma unroll
      for (int n = 0; n < G; n++) { a0[n] = g00; a1[n] = g01; } }
    const float* W0 = ws + OFF_A + (l*2+0)*128*256 + j;
    const float* W1p = ws + OFF_A + (l*2+1)*128*256 + j;
    #pragma unroll 4
    for (int i = 0; i < 128; i++) {
      float w0 = W0[i*256], w1 = W1p[i*256];
      float fv[16];
      *(float4*)&fv[0]  = *(const float4*)&lds[FEAT + i*16];
      *(float4*)&fv[4]  = *(const float4*)&lds[FEAT + i*16 + 4];
      *(float4*)&fv[8]  = *(const float4*)&lds[FEAT + i*16 + 8];
      *(float4*)&fv[12] = *(const float4*)&lds[FEAT + i*16 + 12];
      #pragma unroll
      for (int n = 0; n < G; n++) { a0[n] += fv[n]*w0; a1[n] += fv[n]*w1; }
    }
    #pragma unroll
    for (int n = 0; n < G; n++) lds[GWS + n*512 + j] = a0[n];
    #pragma unroll
    for (int n = 0; n < G; n++) lds[GWS + n*512 + 256 + j] = a1[n];
  }
  if (tid < 2*G) {   // qb[n][h]
    int n = tid >> 1, h = tid & 1;
    float s = ws[OFF_CC + l*2 + h];
    const float* u = ws + OFF_U + (l*2+h)*128;
    for (int i = 0; i < 128; i++) s += lds[FEAT + i*16 + n]*u[i];
    lds[QB + tid] = s;
  }
  __syncthreads();

  const float* nbfeat = (LAYER == 0) ? user_emb : (ws + OFF_NBR);

  // Phase A: all 320 (n,k) scores
  #pragma unroll
  for (int it = 0; it < 2; it++) {
    int p = tid + it*256;
    if (p < G*K) {
      int n = p / K, k = p - n*K;
      float dtf = (float)(imem[16+n] - nbm[320+p]);
      const float4* fr = (const float4*)(nbfeat + (long)nbm[p]*D);
      const float4* g4 = (const float4*)&lds[GWS + n*512];
      float a0 = 0.f, a1 = 0.f;
      #pragma unroll 4
      for (int c = 0; c < 32; c++) {
        float4 f = fr[c];
        float4 g0 = g4[c];
        float4 g1 = g4[64 + c];
        a0 += f.x*g0.x + f.y*g0.y + f.z*g0.z + f.w*g0.w;
        a1 += f.x*g1.x + f.y*g1.y + f.z*g1.z + f.w*g1.w;
      }
      const float4* tw4 = (const float4*)&lds[TW];
      const float4* tb4 = (const float4*)&lds[TB];
      #pragma unroll 2
      for (int c = 0; c < 32; c++) {
        float4 tw = tw4[c], tb = tb4[c];
        float4 cv;
        cv.x = cosr(__fadd_rn(__fmul_rn(dtf, tw.x), tb.x));
        cv.y = cosr(__fadd_rn(__fmul_rn(dtf, tw.y), tb.y));
        cv.z = cosr(__fadd_rn(__fmul_rn(dtf, tw.z), tb.z));
        cv.w = cosr(__fadd_rn(__fmul_rn(dtf, tw.w), tb.w));
        float4 g0 = g4[32 + c];
        float4 g1 = g4[96 + c];
        a0 += cv.x*g0.x + cv.y*g0.y + cv.z*g0.z + cv.w*g0.w;
        a1 += cv.x*g1.x + cv.y*g1.y + cv.z*g1.z + cv.w*g1.w;
      }
      float qb0 = lds[QB + (n<<1)], qb1 = lds[QB + (n<<1) + 1];
      int m = nbm[640+p];
      const float invsq = 0.08838834764831845f;
      lds[AL + n*40 + k]      = m > 0 ? (a0 + qb0)*invsq : -1e9f;
      lds[AL + n*40 + 20 + k] = m > 0 ? (a1 + qb1)*invsq : -1e9f;
    }
  }
  __syncthreads();

  // Phase B: softmax (32 threads)
  if (tid < 2*G) {
    int n = tid >> 1, h = tid & 1;
    float* a = &lds[AL + n*40 + h*20];
    float mx = -1e30f;
    for (int k = 0; k < K; k++) mx = fmaxf(mx, a[k]);
    float s = 0.f;
    for (int k = 0; k < K; k++) { float e = __expf(a[k]-mx); a[k] = e; s += e; }
    float inv = 1.f/s;
    for (int k = 0; k < K; k++) a[k] *= inv;
    if (h == 0) { int any = 0;
      for (int k = 0; k < K; k++) any |= nbm[640 + n*20 + k];
      imem[64+n] = any; }
  }
  __syncthreads();

  // Phase C: wsum[h][e][n] (overwrites g region)
  {
    const int n = tid >> 4, e0 = tid & 15;
    float a0r[K], a1r[K], dtr[K]; int rowr[K];
    #pragma unroll
    for (int k = 0; k < K; k++) {
      a0r[k] = lds[AL + n*40 + k];
      a1r[k] = lds[AL + n*40 + 20 + k];
      dtr[k] = (float)(imem[16+n] - nbm[320 + n*20 + k]);
      rowr[k] = nbm[n*20 + k];
    }
    #pragma unroll
    for (int it = 0; it < 8; it++) {   // feature dims
      int e = e0 + it*16;
      float w0 = 0.f, w1 = 0.f;
      #pragma unroll
      for (int k = 0; k < K; k++) {
        float f = nbfeat[(long)rowr[k]*D + e];
        w0 += a0r[k]*f; w1 += a1r[k]*f;
      }
      lds[GWS + e*16 + n]         = w0;
      lds[GWS + (256+e)*16 + n]   = w1;
    }
    #pragma unroll
    for (int it = 0; it < 8; it++) {   // time dims
      int jj = e0 + it*16;
      float twj = lds[TW+jj], tbj = lds[TB+jj];
      float w0 = 0.f, w1 = 0.f;
      #pragma unroll
      for (int k = 0; k < K; k++) {
        float c = cosr(__fadd_rn(__fmul_rn(dtr[k], twj), tbj));
        w0 += a0r[k]*c; w1 += a1r[k]*c;
      }
      lds[GWS + (128+jj)*16 + n]       = w0;
      lds[GWS + (256+128+jj)*16 + n]   = w1;
    }
  }
  __syncthreads();

  // P6: o = WvT·wsum + bv -> QH[e][n]
  {
    const int e = tid, h = e >> 7;
    float acc[G];
    { float bb = bv[l*E+e];
      #pragma unroll
      for (int n = 0; n < G; n++) acc[n] = bb; }
    const float* W = ws + OFF_WVT + l*65536 + e;
    const float* wsrc = &lds[GWS + h*4096];
    #pragma unroll 8
    for (int j = 0; j < 256; j++) {
      float w = W[j*256];
      float fv[16];
      *(float4*)&fv[0]  = *(const float4*)&wsrc[j*16];
      *(float4*)&fv[4]  = *(const float4*)&wsrc[j*16 + 4];
      *(float4*)&fv[8]  = *(const float4*)&wsrc[j*16 + 8];
      *(float4*)&fv[12] = *(const float4*)&wsrc[j*16 + 12];
      #pragma unroll
      for (int n = 0; n < G; n++) acc[n] += fv[n]*w;
    }
    *(float4*)&lds[QH + e*16]      = make_float4(acc[0],acc[1],acc[2],acc[3]);
    *(float4*)&lds[QH + e*16 + 4]  = make_float4(acc[4],acc[5],acc[6],acc[7]);
    *(float4*)&lds[QH + e*16 + 8]  = make_float4(acc[8],acc[9],acc[10],acc[11]);
    *(float4*)&lds[QH + e*16 + 12] = make_float4(acc[12],acc[13],acc[14],acc[15]);
  }
  __syncthreads();

  // P7: oo = WoT·o + bo (anyv mask) -> GWS[0:4096] [e][n]
  {
    const int e = tid;
    float acc[G];
    { float bb = bo[l*E+e];
      #pragma unroll
      for (int n = 0; n < G; n++) acc[n] = bb; }
    const float* W = ws + OFF_WOT + l*65536 + e;
    #pragma unroll 8
    for (int i = 0; i < 256; i++) {
      float w = W[i*256];
      float fv[16];
      *(float4*)&fv[0]  = *(const float4*)&lds[QH + i*16];
      *(float4*)&fv[4]  = *(const float4*)&lds[QH + i*16 + 4];
      *(float4*)&fv[8]  = *(const float4*)&lds[QH + i*16 + 8];
      *(float4*)&fv[12] = *(const float4*)&lds[QH + i*16 + 12];
      #pragma unroll
      for (int n = 0; n < G; n++) acc[n] += fv[n]*w;
    }
    float v[G];
    #pragma unroll
    for (int n = 0; n < G; n++) v[n] = imem[64+n] ? acc[n] : 0.f;
    *(float4*)&lds[GWS + e*16]      = make_float4(v[0],v[1],v[2],v[3]);
    *(float4*)&lds[GWS + e*16 + 4]  = make_float4(v[4],v[5],v[6],v[7]);
    *(float4*)&lds[GWS + e*16 + 8]  = make_float4(v[8],v[9],v[10],v[11]);
    *(float4*)&lds[GWS + e*16 + 12] = make_float4(v[12],v[13],v[14],v[15]);
  }
  __syncthreads();

  // FFN1 partials -> QH
  {
    const int dd = tid & 127, half = tid >> 7;
    float acc[G];
    #pragma unroll
    for (int n = 0; n < G; n++) acc[n] = 0.f;
    const float* W = ws + OFF_W1T + l*384*D + dd;
    if (half == 0) {
      #pragma unroll 8
      for (int i = 0; i < 192; i++) {
        float w = W[i*D];
        float fv[16];
        *(float4*)&fv[0]  = *(const float4*)&lds[GWS + i*16];
        *(float4*)&fv[4]  = *(const float4*)&lds[GWS + i*16 + 4];
        *(float4*)&fv[8]  = *(const float4*)&lds[GWS + i*16 + 8];
        *(float4*)&fv[12] = *(const float4*)&lds[GWS + i*16 + 12];
        #pragma unroll
        for (int n = 0; n < G; n++) acc[n] += fv[n]*w;
      }
    } else {
      #pragma unroll 8
      for (int i = 192; i < 256; i++) {
        float w = W[i*D];
        float fv[16];
        *(float4*)&fv[0]  = *(const float4*)&lds[GWS + i*16];
        *(float4*)&fv[4]  = *(const float4*)&lds[GWS + i*16 + 4];
        *(float4*)&fv[8]  = *(const float4*)&lds[GWS + i*16 + 8];
        *(float4*)&fv[12] = *(const float4*)&lds[GWS + i*16 + 12];
        #pragma unroll
        for (int n = 0; n < G; n++) acc[n] += fv[n]*w;
      }
      #pragma unroll 8
      for (int i = 0; i < 128; i++) {
        float w = W[(256+i)*D];
        float fv[16];
        *(float4*)&fv[0]  = *(const float4*)&lds[FEAT + i*16];
        *(float4*)&fv[4]  = *(const float4*)&lds[FEAT + i*16 + 4];
        *(float4*)&fv[8]  = *(const float4*)&lds[FEAT + i*16 + 8];
        *(float4*)&fv[12] = *(const float4*)&lds[FEAT + i*16 + 12];
        #pragma unroll
        for (int n = 0; n < G; n++) acc[n] += fv[n]*w;
      }
    }
    *(float4*)&lds[QH + (half*128+dd)*16]      = make_float4(acc[0],acc[1],acc[2],acc[3]);
    *(float4*)&lds[QH + (half*128+dd)*16 + 4]  = make_float4(acc[4],acc[5],acc[6],acc[7]);
    *(float4*)&lds[QH + (half*128+dd)*16 + 8]  = make_float4(acc[8],acc[9],acc[10],acc[11]);
    *(float4*)&lds[QH + (half*128+dd)*16 + 12] = make_float4(acc[12],acc[13],acc[14],acc[15]);
  }
  __syncthreads();
  // h1 combine -> H1R
  #pragma unroll
  for (int it = 0; it < 8; it++) {
    int idx = tid + it*256, dd = idx >> 4, n = idx & 15;
    float v = lds[QH + dd*16 + n] + lds[QH + (128+dd)*16 + n] + b1[l*D + dd];
    lds[H1R + dd*16 + n] = fmaxf(v, 0.f);
  }
  __syncthreads();

  // FFN2 partials -> QH
  {
    const int dd = tid & 127, half = tid >> 7;
    float acc[G];
    #pragma unroll
    for (int n = 0; n < G; n++) acc[n] = 0.f;
    const float* W = ws + OFF_W2T + l*D*D + dd;
    #pragma unroll 8
    for (int i = half*64; i < half*64 + 64; i++) {
      float w = W[i*D];
      float fv[16];
      *(float4*)&fv[0]  = *(const float4*)&lds[H1R + i*16];
      *(float4*)&fv[4]  = *(const float4*)&lds[H1R + i*16 + 4];
      *(float4*)&fv[8]  = *(const float4*)&lds[H1R + i*16 + 8];
      *(float4*)&fv[12] = *(const float4*)&lds[H1R + i*16 + 12];
      #pragma unroll
      for (int n = 0; n < G; n++) acc[n] += fv[n]*w;
    }
    *(float4*)&lds[QH + (half*128+dd)*16]      = make_float4(acc[0],acc[1],acc[2],acc[3]);
    *(float4*)&lds[QH + (half*128+dd)*16 + 4]  = make_float4(acc[4],acc[5],acc[6],acc[7]);
    *(float4*)&lds[QH + (half*128+dd)*16 + 8]  = make_float4(acc[8],acc[9],acc[10],acc[11]);
    *(float4*)&lds[QH + (half*128+dd)*16 + 12] = make_float4(acc[12],acc[13],acc[14],acc[15]);
  }
  __syncthreads();
  // out combine (n fastest for conflict-free LDS reads)
  #pragma unroll
  for (int it = 0; it < 8; it++) {
    int idx = tid + it*256, n = idx & 15, dd = idx >> 4;
    float v = lds[QH + dd*16 + n] + lds[QH + (128+dd)*16 + n] + b2[l*D + dd];
    if (LAYER == 0) { if (imem[80+n]) ws[OFF_NBR + (long)imem[48+n]*D + dd] = v; }
    else            out[(long)(blk*G + n)*D + dd] = v;
  }
}

extern "C" void kernel_launch(void* const* d_in, const int* in_sizes, int n_in,
                              void* d_out, int out_size, void* d_ws, size_t ws_size,
                              hipStream_t stream) {
  const int* nodes  = (const int*)d_in[0];
  const int* edges  = (const int*)d_in[1];
  const int* tst    = (const int*)d_in[2];
  const int* u_neig = (const int*)d_in[4];
  const int* u_edges= (const int*)d_in[5];
  const int* u_times= (const int*)d_in[6];
  const int* u_mask = (const int*)d_in[7];
  const int* i_neig = (const int*)d_in[8];
  const int* i_times= (const int*)d_in[10];
  const int* i_mask = (const int*)d_in[11];
  const float* user_emb = (const float*)d_in[12];
  const float* item_emb = (const float*)d_in[13];
  const float* time_w = (const float*)d_in[14];
  const float* time_b = (const float*)d_in[15];
  const float* Wq = (const float*)d_in[16]; const float* bq = (const float*)d_in[17];
  const float* Wk = (const float*)d_in[18]; const float* bk = (const float*)d_in[19];
  const float* Wv = (const float*)d_in[20]; const float* bv = (const float*)d_in[21];
  const float* Wo = (const float*)d_in[22]; const float* bo = (const float*)d_in[23];
  const float* W1 = (const float*)d_in[24]; const float* b1 = (const float*)d_in[25];
  const float* W2 = (const float*)d_in[26]; const float* b2 = (const float*)d_in[27];
  float* ws = (float*)d_ws;
  float* out = (float*)d_out;

  precompute1<<<dim3(512), dim3(256), 0, stream>>>(Wv, Wo, W1, W2, Wq, bq, time_b, ws);
  precompute2<<<dim3(516), dim3(256), 0, stream>>>(Wq, Wk, bk, ws);
  zero_cnt<<<dim3(1), dim3(64), 0, stream>>>(ws);
  compact_valid<<<dim3(160), dim3(256), 0, stream>>>(edges, u_mask, ws);

  attend<0><<<dim3(NSLOT/G), dim3(256), 0, stream>>>(
      nodes, edges, tst, u_edges, u_neig, u_times, u_mask,
      i_neig, i_times, i_mask, user_emb, item_emb, time_w, time_b,
      bv, bo, b1, b2, ws, out);

  attend<1><<<dim3(NB_B/G), dim3(256), 0, stream>>>(
      nodes, edges, tst, u_edges, u_neig, u_times, u_mask,
      i_neig, i_times, i_mask, user_emb, item_emb, time_w, time_b,
      bv, bo, b1, b2, ws, out);
}

// Round 7
// 184.708 us; speedup vs baseline: 20.8240x; 2.1192x over previous
//
#include <hip/hip_runtime.h>
#include <hip/hip_bf16.h>

#define TBL 50
#define K 20
#define D 128
#define E 256
#define NB_B 2048
#define NSLOT (NB_B*K)     // 40960
#define G 16

typedef unsigned short ushort;
typedef unsigned short ushort8 __attribute__((ext_vector_type(8)));
typedef float f32x4 __attribute__((ext_vector_type(4)));
typedef __bf16 bf16x8 __attribute__((ext_vector_type(8)));

// ws float offsets
#define OFF_GC   0               // [l2][512] f32 (n = h*256+j)
#define OFF_U    1024            // [l2*2][128] f32
#define OFF_CC   1536            // [4] f32
#define OFF_QC   1540            // [l2][256] f32
#define OFF_PKF  2052            // packed bf16 weights (ushort region, 524288 sh)
#define OFF_NBR  264196          // [40960][128] f32
#define OFF_CNT  5507076         // int count; int compact[40960]
// ushort offsets inside PK region
#define APKo   0                 // [l2][ (nt32*4+kk)*64+lane ][8]
#define VPKo   131072            // [l2*h2][ (nt8*8+kk)*64+lane ][8]
#define OPKo   262144            // [l2][ (nt16*8+kk)*64+lane ][8]
#define W1PKo  393216            // [l2][ (nt8*12+kk)*64+lane ][8]
#define W2PKo  491520            // [l2][ (nt8*4+kk)*64+lane ][8]

__device__ __forceinline__ float cosr(float x) {
  float kf = rintf(x * 0.15915494309189535f);
  float r = __fmaf_rn(kf, -6.28125f, x);
  r = __fmaf_rn(kf, -1.9353071795864769e-3f, r);
  return __cosf(r);
}
__device__ __forceinline__ float b2f(ushort u) {
  return __uint_as_float(((unsigned)u) << 16);
}
__device__ __forceinline__ ushort cvtbf(float f) {
  unsigned u = __float_as_uint(f);
  return (ushort)((u + 0x7FFF + ((u >> 16) & 1)) >> 16);
}
__device__ __forceinline__ bf16x8 ldb8(const ushort* p) {
  union { ushort8 u; bf16x8 b; } c;
  c.u = *(const ushort8*)p;
  return c.b;
}

__global__ __launch_bounds__(256) void precompute1(
    const float* __restrict__ Wq, const float* __restrict__ bq,
    const float* __restrict__ time_b, float* __restrict__ ws)
{
  int idx = blockIdx.x*256 + threadIdx.x;
  if (idx < 512) { int l = idx>>8;
    float a = bq[idx];
    for (int t = 0; t < 128; t++) a += Wq[l*65536 + (idx&255)*256 + 128 + t]*cosf(time_b[t]);
    ws[OFF_QC+idx] = a; }
}

__global__ __launch_bounds__(256) void precompute2(
    const float* __restrict__ Wq, const float* __restrict__ Wk,
    const float* __restrict__ bk, float* __restrict__ ws)
{
  int b = blockIdx.x, t = threadIdx.x;
  ushort* wsu = (ushort*)(ws + OFF_PKF);
  if (b < 512) {           // A[l][h][i][j], j = t -> APK bf16
    int l = b >> 8, h = (b >> 7) & 1, i = b & 127;
    float s = 0.f;
    const float* wq = Wq + l*65536 + h*32768 + i;
    const float* wk = Wk + l*65536 + h*32768 + t;
    for (int m = 0; m < 128; m++) s += wq[m*256]*wk[m*256];
    int N = h*256 + t;
    int nt = N >> 4, cl = N & 15;
    int kk = i >> 5, ch = (i >> 3) & 3, bb = i & 7;
    wsu[APKo + (long)l*65536 + (((nt*4+kk)*64 + ch*16 + cl)*8) + bb] = cvtbf(s);
  } else {
    int q = b - 512, l = q >> 1, h = q & 1;
    { float s = 0.f;      // gc
      const float* qc = ws + OFF_QC + l*256 + h*128;
      const float* wk = Wk + l*65536 + h*32768 + t;
      for (int m = 0; m < 128; m++) s += qc[m]*wk[m*256];
      ws[OFF_GC + l*512 + h*256 + t] = s; }
    if (t < 128) {        // u
      float s = 0.f;
      const float* wq = Wq + l*65536 + h*32768 + t;
      const float* bkp = bk + l*256 + h*128;
      for (int m = 0; m < 128; m++) s += wq[m*256]*bkp[m];
      ws[OFF_U + (l*2+h)*128 + t] = s; }
    if (t == 254) {       // cc
      float s = 0.f;
      const float* qc = ws + OFF_QC + l*256 + h*128;
      const float* bkp = bk + l*256 + h*128;
      for (int m = 0; m < 128; m++) s += qc[m]*bkp[m];
      ws[OFF_CC + l*2+h] = s; }
  }
}

__global__ __launch_bounds__(256) void packw(
    const float* __restrict__ Wv, const float* __restrict__ Wo,
    const float* __restrict__ W1, const float* __restrict__ W2,
    float* __restrict__ ws)
{
  int idx = blockIdx.x*256 + threadIdx.x;   // < 393216
  ushort* wsu = (ushort*)(ws + OFF_PKF);
  if (idx < 131072) {          // VPK
    int q = idx >> 15, r = idx & 32767, l = q >> 1, h = q & 1;
    int bb = r & 7, lane = (r >> 3) & 63, kk = (r >> 9) & 7, nt = r >> 12;
    int k = kk*32 + (lane>>4)*8 + bb, d = nt*16 + (lane&15);
    wsu[VPKo + idx] = cvtbf(Wv[l*65536 + (h*128+d)*256 + k]);
  } else if (idx < 262144) {   // OPK
    int rel = idx - 131072, l = rel >> 16, r = rel & 65535;
    int bb = r & 7, lane = (r >> 3) & 63, kk = (r >> 9) & 7, nt = r >> 12;
    int k = kk*32 + (lane>>4)*8 + bb, e = nt*16 + (lane&15);
    wsu[OPKo + rel] = cvtbf(Wo[l*65536 + e*256 + k]);
  } else if (idx < 360448) {   // W1PK
    int rel = idx - 262144, l = rel / 49152, r = rel % 49152;
    int nt = r / 6144, rr = r - nt*6144;
    int kk = rr >> 9, lane = (rr >> 3) & 63, bb = rr & 7;
    int k = kk*32 + (lane>>4)*8 + bb, d = nt*16 + (lane&15);
    wsu[W1PKo + rel] = cvtbf(W1[l*49152 + d*384 + k]);
  } else {                     // W2PK
    int rel = idx - 360448, l = rel >> 14, r = rel & 16383;
    int nt = r >> 11, rr = r & 2047;
    int kk = rr >> 9, lane = (rr >> 3) & 63, bb = rr & 7;
    int k = kk*32 + (lane>>4)*8 + bb, d = nt*16 + (lane&15);
    wsu[W2PKo + rel] = cvtbf(W2[l*16384 + d*128 + k]);
  }
}

__global__ void zero_cnt(float* __restrict__ ws)
{
  if (threadIdx.x == 0) *(int*)(ws + OFF_CNT) = 0;
}

__global__ __launch_bounds__(256) void compact_valid(
    const int* __restrict__ edges, const int* __restrict__ u_mask,
    float* __restrict__ ws)
{
  int idx = blockIdx.x*256 + threadIdx.x;    // < 40960
  int b = idx / K, s = idx - b*K;
  int pe = edges[b];
  if (u_mask[pe*TBL + (TBL-K) + s] > 0) {
    int pos = atomicAdd((int*)(ws + OFF_CNT), 1);
    ((int*)(ws + OFF_CNT))[1 + pos] = idx;
  }
}

template<int LAYER>
__global__ __launch_bounds__(256, 3) void attend(
    const int* __restrict__ nodes, const int* __restrict__ edges, const int* __restrict__ tstamps,
    const int* __restrict__ u_edges, const int* __restrict__ u_neig,
    const int* __restrict__ u_times, const int* __restrict__ u_mask,
    const int* __restrict__ i_neig, const int* __restrict__ i_times, const int* __restrict__ i_mask,
    const float* __restrict__ user_emb, const float* __restrict__ item_emb,
    const float* __restrict__ time_w, const float* __restrict__ time_b,
    const float* __restrict__ bv, const float* __restrict__ bo,
    const float* __restrict__ b1, const float* __restrict__ b2,
    float* __restrict__ wsf, float* __restrict__ out)
{
  __shared__ __align__(16) ushort sOP2[16*392];  // [oo(256) | feat(128) | pad]
  __shared__ __align__(16) ushort sGWS[16*520];  // g then wsum [h*256+j]
  __shared__ __align__(16) ushort sOP1[16*264];  // o then h1
  __shared__ float sTW[128], sTB[128], sAL[640], sQB[32];
  __shared__ int imem[96];   // 0 nid,16 ntime,32 erow,48 slot,64 anyv,80 act
  __shared__ int nbm[960];   // [0:320) row, [320:640) time, [640:960) mask

  const int tid = threadIdx.x, blk = blockIdx.x, l = LAYER;
  const int lane = tid & 63, wv = tid >> 6;
  const int col = lane & 15, chunk = lane >> 4;
  const ushort* wsu = (const ushort*)(wsf + OFF_PKF);

  int count = (LAYER == 0) ? *(const int*)(wsf + OFF_CNT) : NB_B;
  if (blk*G >= count) return;

  if (tid < G) {
    int idx = blk*G + tid; int act = idx < count ? 1 : 0;
    int slot, nid, ntm, erow;
    if (LAYER == 0) {
      int ii = act ? idx : 0;
      slot = ((const int*)(wsf + OFF_CNT))[1 + ii];
      int bb = slot / K, s = slot - bb*K;
      int base = edges[bb]*TBL + (TBL-K) + s;
      nid = u_neig[base]; ntm = u_times[base]; erow = u_edges[base];
    } else { slot = idx; nid = nodes[idx]; ntm = tstamps[idx]; erow = edges[idx]; }
    imem[tid] = nid; imem[16+tid] = ntm; imem[32+tid] = erow;
    imem[48+tid] = slot; imem[80+tid] = act;
  }
  if (tid < 128) { sTW[tid] = time_w[tid]; sTB[tid] = time_b[tid]; }
  __syncthreads();

  // P0: gather feat -> OP2 cols 256..383 (bf16); neighbor meta
  const float* nemb = (LAYER == 0) ? item_emb : user_emb;
  #pragma unroll
  for (int it = 0; it < 8; it++) {
    int idx = tid + it*256, n = idx >> 7, i = idx & 127;
    sOP2[n*392 + 256 + i] = cvtbf(nemb[(long)imem[n]*D + i]);
  }
  #pragma unroll
  for (int it = 0; it < 2; it++) {
    int p = tid + it*256;
    if (p < G*K) {
      int n = p / K, k = p - n*K;
      int base = imem[32+n]*TBL + (TBL-K) + k;
      if (LAYER == 0) { nbm[p] = i_neig[base]; nbm[320+p] = i_times[base]; nbm[640+p] = i_mask[base]; }
      else            { nbm[p] = (blk*G+n)*K + k; nbm[320+p] = u_times[base]; nbm[640+p] = u_mask[base]; }
    }
  }
  __syncthreads();

  // G1: g[16x512] = feat[16x128] @ A  (+gc), -> sGWS bf16
  {
    bf16x8 a[4];
    #pragma unroll
    for (int kk = 0; kk < 4; kk++)
      a[kk] = ldb8(&sOP2[col*392 + 256 + kk*32 + chunk*8]);
    f32x4 acc[8];
    #pragma unroll
    for (int t = 0; t < 8; t++) acc[t] = (f32x4){0.f,0.f,0.f,0.f};
    const ushort* BP = wsu + APKo + (long)l*65536;
    #pragma unroll
    for (int t = 0; t < 8; t++) {
      int nt = wv*8 + t;
      #pragma unroll
      for (int kk = 0; kk < 4; kk++) {
        bf16x8 b = ldb8(&BP[((nt*4+kk)*64 + lane)*8]);
        acc[t] = __builtin_amdgcn_mfma_f32_16x16x32_bf16(a[kk], b, acc[t], 0, 0, 0);
      }
    }
    #pragma unroll
    for (int t = 0; t < 8; t++) {
      int N = (wv*8+t)*16 + col;
      float gcv = wsf[OFF_GC + l*512 + N];
      #pragma unroll
      for (int r = 0; r < 4; r++)
        sGWS[(chunk*4+r)*520 + N] = cvtbf(acc[t][r] + gcv);
    }
  }
  if (tid < 32) {   // qb[n][h]
    int n = tid >> 1, h = tid & 1;
    float s = wsf[OFF_CC + l*2 + h];
    const float* u = wsf + OFF_U + (l*2+h)*128;
    for (int i = 0; i < 128; i++) s += b2f(sOP2[n*392 + 256 + i])*u[i];
    sQB[tid] = s;
  }
  __syncthreads();

  const float* nbfeat = (LAYER == 0) ? user_emb : (wsf + OFF_NBR);

  // Phase A: 320 scores, balanced 80/wave
  {
    auto scoreItem = [&](int p) {
      int n = p / K, k = p - n*K;
      float dtf = (float)(imem[16+n] - nbm[320+p]);
      const float4* fr = (const float4*)(nbfeat + (long)nbm[p]*D);
      const ushort8* gp = (const ushort8*)&sGWS[n*520];
      float a0 = 0.f, a1 = 0.f;
      #pragma unroll 4
      for (int c = 0; c < 16; c++) {
        float4 f0 = fr[2*c], f1 = fr[2*c+1];
        ushort8 g0 = gp[c], g1 = gp[32+c];
        a0 += f0.x*b2f(g0[0]) + f0.y*b2f(g0[1]) + f0.z*b2f(g0[2]) + f0.w*b2f(g0[3])
            + f1.x*b2f(g0[4]) + f1.y*b2f(g0[5]) + f1.z*b2f(g0[6]) + f1.w*b2f(g0[7]);
        a1 += f0.x*b2f(g1[0]) + f0.y*b2f(g1[1]) + f0.z*b2f(g1[2]) + f0.w*b2f(g1[3])
            + f1.x*b2f(g1[4]) + f1.y*b2f(g1[5]) + f1.z*b2f(g1[6]) + f1.w*b2f(g1[7]);
      }
      #pragma unroll 2
      for (int c = 0; c < 16; c++) {
        ushort8 g0 = gp[16+c], g1 = gp[48+c];
        float a0c = 0.f, a1c = 0.f;
        #pragma unroll
        for (int j = 0; j < 8; j++) {
          float cv = cosr(__fadd_rn(__fmul_rn(dtf, sTW[c*8+j]), sTB[c*8+j]));
          a0c += cv*b2f(g0[j]); a1c += cv*b2f(g1[j]);
        }
        a0 += a0c; a1 += a1c;
      }
      int m = nbm[640+p];
      const float invsq = 0.08838834764831845f;
      sAL[n*40 + k]      = m > 0 ? (a0 + sQB[n*2])*invsq   : -1e9f;
      sAL[n*40 + 20 + k] = m > 0 ? (a1 + sQB[n*2+1])*invsq : -1e9f;
    };
    scoreItem(wv*80 + lane);
    if (lane < 16) scoreItem(wv*80 + 64 + lane);
  }
  __syncthreads();

  // softmax
  if (tid < 2*G) {
    int n = tid >> 1, h = tid & 1;
    float* a = &sAL[n*40 + h*20];
    float mx = -1e30f;
    for (int k = 0; k < K; k++) mx = fmaxf(mx, a[k]);
    float s = 0.f;
    for (int k = 0; k < K; k++) { float e = __expf(a[k]-mx); a[k] = e; s += e; }
    float inv = 1.f/s;
    for (int k = 0; k < K; k++) a[k] *= inv;
    if (h == 0) { int any = 0;
      for (int k = 0; k < K; k++) any |= nbm[640 + n*20 + k];
      imem[64+n] = any; }
  }
  __syncthreads();

  // Phase C: wsum -> sGWS bf16 rows [n][h*256+j]
  {
    const int n = tid >> 4, e0 = tid & 15;
    float a0r[K], a1r[K], dtr[K]; int rowr[K];
    #pragma unroll
    for (int k = 0; k < K; k++) {
      a0r[k] = sAL[n*40 + k]; a1r[k] = sAL[n*40 + 20 + k];
      dtr[k] = (float)(imem[16+n] - nbm[320 + n*20 + k]);
      rowr[k] = nbm[n*20 + k];
    }
    #pragma unroll
    for (int it = 0; it < 8; it++) {
      int e = e0 + it*16;
      float w0 = 0.f, w1 = 0.f;
      #pragma unroll
      for (int k = 0; k < K; k++) {
        float f = nbfeat[(long)rowr[k]*D + e];
        w0 += a0r[k]*f; w1 += a1r[k]*f;
      }
      sGWS[n*520 + e]       = cvtbf(w0);
      sGWS[n*520 + 256 + e] = cvtbf(w1);
    }
    #pragma unroll
    for (int it = 0; it < 8; it++) {
      int jj = e0 + it*16;
      float twj = sTW[jj], tbj = sTB[jj];
      float w0 = 0.f, w1 = 0.f;
      #pragma unroll
      for (int k = 0; k < K; k++) {
        float c = cosr(__fadd_rn(__fmul_rn(dtr[k], twj), tbj));
        w0 += a0r[k]*c; w1 += a1r[k]*c;
      }
      sGWS[n*520 + 128 + jj] = cvtbf(w0);
      sGWS[n*520 + 384 + jj] = cvtbf(w1);
    }
  }
  __syncthreads();

  // G2: o = wsum_h @ Wv_h (+bv) -> sOP1
  {
    int h = wv >> 1, ntb = (wv & 1)*4;
    bf16x8 a[8];
    #pragma unroll
    for (int kk = 0; kk < 8; kk++)
      a[kk] = ldb8(&sGWS[col*520 + h*256 + kk*32 + chunk*8]);
    f32x4 acc[4];
    #pragma unroll
    for (int t = 0; t < 4; t++) acc[t] = (f32x4){0.f,0.f,0.f,0.f};
    const ushort* BP = wsu + VPKo + (long)(l*2+h)*32768;
    #pragma unroll
    for (int t = 0; t < 4; t++) {
      int nt = ntb + t;
      #pragma unroll
      for (int kk = 0; kk < 8; kk++) {
        bf16x8 b = ldb8(&BP[((nt*8+kk)*64 + lane)*8]);
        acc[t] = __builtin_amdgcn_mfma_f32_16x16x32_bf16(a[kk], b, acc[t], 0, 0, 0);
      }
    }
    #pragma unroll
    for (int t = 0; t < 4; t++) {
      int ocol = h*128 + (ntb+t)*16 + col;
      float bb = bv[l*256 + ocol];
      #pragma unroll
      for (int r = 0; r < 4; r++)
        sOP1[(chunk*4+r)*264 + ocol] = cvtbf(acc[t][r] + bb);
    }
  }
  __syncthreads();

  // G3: oo = o @ Wo (+bo, anyv mask) -> sOP2 cols 0..255
  {
    bf16x8 a[8];
    #pragma unroll
    for (int kk = 0; kk < 8; kk++)
      a[kk] = ldb8(&sOP1[col*264 + kk*32 + chunk*8]);
    f32x4 acc[4];
    #pragma unroll
    for (int t = 0; t < 4; t++) acc[t] = (f32x4){0.f,0.f,0.f,0.f};
    const ushort* BP = wsu + OPKo + (long)l*65536;
    #pragma unroll
    for (int t = 0; t < 4; t++) {
      int nt = wv*4 + t;
      #pragma unroll
      for (int kk = 0; kk < 8; kk++) {
        bf16x8 b = ldb8(&BP[((nt*8+kk)*64 + lane)*8]);
        acc[t] = __builtin_amdgcn_mfma_f32_16x16x32_bf16(a[kk], b, acc[t], 0, 0, 0);
      }
    }
    #pragma unroll
    for (int t = 0; t < 4; t++) {
      int e = (wv*4+t)*16 + col;
      float bb = bo[l*256 + e];
      #pragma unroll
      for (int r = 0; r < 4; r++) {
        int row = chunk*4 + r;
        float v = imem[64+row] ? (acc[t][r] + bb) : 0.f;
        sOP2[row*392 + e] = cvtbf(v);
      }
    }
  }
  __syncthreads();

  // G4: h1 = [oo,feat] @ W1 (+b1, relu) -> sOP1 cols 0..127
  {
    bf16x8 a[12];
    #pragma unroll
    for (int kk = 0; kk < 12; kk++)
      a[kk] = ldb8(&sOP2[col*392 + kk*32 + chunk*8]);
    f32x4 acc[2];
    acc[0] = (f32x4){0.f,0.f,0.f,0.f}; acc[1] = (f32x4){0.f,0.f,0.f,0.f};
    const ushort* BP = wsu + W1PKo + (long)l*49152;
    #pragma unroll
    for (int t = 0; t < 2; t++) {
      int nt = wv*2 + t;
      #pragma unroll
      for (int kk = 0; kk < 12; kk++) {
        bf16x8 b = ldb8(&BP[((nt*12+kk)*64 + lane)*8]);
        acc[t] = __builtin_amdgcn_mfma_f32_16x16x32_bf16(a[kk], b, acc[t], 0, 0, 0);
      }
    }
    #pragma unroll
    for (int t = 0; t < 2; t++) {
      int dcol = (wv*2+t)*16 + col;
      float bb = b1[l*128 + dcol];
      #pragma unroll
      for (int r = 0; r < 4; r++)
        sOP1[(chunk*4+r)*264 + dcol] = cvtbf(fmaxf(acc[t][r] + bb, 0.f));
    }
  }
  __syncthreads();

  // G5: out = h1 @ W2 (+b2) -> global f32
  {
    bf16x8 a[4];
    #pragma unroll
    for (int kk = 0; kk < 4; kk++)
      a[kk] = ldb8(&sOP1[col*264 + kk*32 + chunk*8]);
    f32x4 acc[2];
    acc[0] = (f32x4){0.f,0.f,0.f,0.f}; acc[1] = (f32x4){0.f,0.f,0.f,0.f};
    const ushort* BP = wsu + W2PKo + (long)l*16384;
    #pragma unroll
    for (int t = 0; t < 2; t++) {
      int nt = wv*2 + t;
      #pragma unroll
      for (int kk = 0; kk < 4; kk++) {
        bf16x8 b = ldb8(&BP[((nt*4+kk)*64 + lane)*8]);
        acc[t] = __builtin_amdgcn_mfma_f32_16x16x32_bf16(a[kk], b, acc[t], 0, 0, 0);
      }
    }
    #pragma unroll
    for (int t = 0; t < 2; t++) {
      int dcol = (wv*2+t)*16 + col;
      float bb = b2[l*128 + dcol];
      #pragma unroll
      for (int r = 0; r < 4; r++) {
        int row = chunk*4 + r;
        float v = acc[t][r] + bb;
        if (LAYER == 0) { if (imem[80+row]) wsf[OFF_NBR + (long)imem[48+row]*D + dcol] = v; }
        else            out[(long)(blk*G + row)*D + dcol] = v;
      }
    }
  }
}

extern "C" void kernel_launch(void* const* d_in, const int* in_sizes, int n_in,
                              void* d_out, int out_size, void* d_ws, size_t ws_size,
                              hipStream_t stream) {
  const int* nodes  = (const int*)d_in[0];
  const int* edges  = (const int*)d_in[1];
  const int* tst    = (const int*)d_in[2];
  const int* u_neig = (const int*)d_in[4];
  const int* u_edges= (const int*)d_in[5];
  const int* u_times= (const int*)d_in[6];
  const int* u_mask = (const int*)d_in[7];
  const int* i_neig = (const int*)d_in[8];
  const int* i_times= (const int*)d_in[10];
  const int* i_mask = (const int*)d_in[11];
  const float* user_emb = (const float*)d_in[12];
  const float* item_emb = (const float*)d_in[13];
  const float* time_w = (const float*)d_in[14];
  const float* time_b = (const float*)d_in[15];
  const float* Wq = (const float*)d_in[16]; const float* bq = (const float*)d_in[17];
  const float* Wk = (const float*)d_in[18]; const float* bk = (const float*)d_in[19];
  const float* Wv = (const float*)d_in[20]; const float* bv = (const float*)d_in[21];
  const float* Wo = (const float*)d_in[22]; const float* bo = (const float*)d_in[23];
  const float* W1 = (const float*)d_in[24]; const float* b1 = (const float*)d_in[25];
  const float* W2 = (const float*)d_in[26]; const float* b2 = (const float*)d_in[27];
  float* ws = (float*)d_ws;
  float* out = (float*)d_out;

  precompute1<<<dim3(2), dim3(256), 0, stream>>>(Wq, bq, time_b, ws);
  precompute2<<<dim3(516), dim3(256), 0, stream>>>(Wq, Wk, bk, ws);
  packw<<<dim3(1536), dim3(256), 0, stream>>>(Wv, Wo, W1, W2, ws);
  zero_cnt<<<dim3(1), dim3(64), 0, stream>>>(ws);
  compact_valid<<<dim3(160), dim3(256), 0, stream>>>(edges, u_mask, ws);

  attend<0><<<dim3(NSLOT/G), dim3(256), 0, stream>>>(
      nodes, edges, tst, u_edges, u_neig, u_times, u_mask,
      i_neig, i_times, i_mask, user_emb, item_emb, time_w, time_b,
      bv, bo, b1, b2, ws, out);

  attend<1><<<dim3(NB_B/G), dim3(256), 0, stream>>>(
      nodes, edges, tst, u_edges, u_neig, u_times, u_mask,
      i_neig, i_times, i_mask, user_emb, item_emb, time_w, time_b,
      bv, bo, b1, b2, ws, out);
}